// Round 8
// baseline (328.588 us; speedup 1.0000x reference)
//
#include <hip/hip_runtime.h>
#include <hip/hip_bf16.h>
#include <cstdint>

typedef __attribute__((ext_vector_type(8))) __bf16 bf16x8;
typedef __attribute__((ext_vector_type(4))) __bf16 bf16x4;
typedef __attribute__((ext_vector_type(4))) float f32x4;
typedef unsigned int uint32;
typedef unsigned short uint16;

#define LDS_AS __attribute__((address_space(3)))
#define GLB_AS __attribute__((address_space(1)))

static __device__ __forceinline__ void gld_lds16(const void* g, LDS_AS char* l) {
  __builtin_amdgcn_global_load_lds((const GLB_AS uint32*)g, (LDS_AS uint32*)l, 16, 0, 0);
}

#define MFMA(a, b, c) __builtin_amdgcn_mfma_f32_16x16x32_bf16((a), (b), (c), 0, 0, 0)

// 3-term split-bf16 MFMA: A*B ~= Ah*Bh + Al*Bh + Ah*Bl
static __device__ __forceinline__ f32x4 mfma3(bf16x8 ah, bf16x8 al, bf16x8 bh,
                                              bf16x8 bl, f32x4 c) {
  c = MFMA(ah, bh, c);
  c = MFMA(al, bh, c);
  c = MFMA(ah, bl, c);
  return c;
}

static __device__ __forceinline__ uint32 pack_bf16(float a, float b) {
  __bf16 ha = (__bf16)a, hb = (__bf16)b;
  return (uint32)__builtin_bit_cast(uint16, ha) |
         ((uint32)__builtin_bit_cast(uint16, hb) << 16);
}

// XOR swizzle: spreads stride-128B rows across banks (T2, rule #21 both-sides)
#define KB(row, colbyte) ((((row) * 128 + (colbyte))) ^ (((row) & 7) << 4))

// ---------------------------------------------------------------------------
// prep_all: one dispatch for all input preprocessing.
//  blocks 0..1023     : K f32 -> split bf16 hi/lo swizzled images KH/KL
//  blocks 1024..2047  : V f32 -> V^T swizzled image, k-pairs packed u32
//  blocks 2048..3071  : Wf  transpose -> bf16 WFT  [1024x1024]
//  blocks 3072..7167  : W1  transpose -> bf16 W1T  [4096x1024]
//  blocks 7168..11263 : W2  transpose -> bf16 W2T  [1024x4096]
// ---------------------------------------------------------------------------
__global__ __launch_bounds__(256) void prep_all(
    const float* __restrict__ K, const float* __restrict__ V,
    char* __restrict__ KH, char* __restrict__ KL, char* __restrict__ VT,
    const float* __restrict__ Wf, __bf16* __restrict__ WFT,
    const float* __restrict__ W1, __bf16* __restrict__ W1T,
    const float* __restrict__ W2, __bf16* __restrict__ W2T) {
  int b = blockIdx.x;
  if (b < 1024) {
    int kt = b & 15, h = b >> 4;
    const float* src = K + (size_t)h * 65536 + kt * 4096;
    char* dh = KH + (size_t)(h * 16 + kt) * 8192;
    char* dl = KL + (size_t)(h * 16 + kt) * 8192;
    int r = threadIdx.x >> 2, cq = threadIdx.x & 3;
    const float* sp = src + r * 64 + cq * 16;
    bf16x8 h0, l0, h1, l1;
#pragma unroll
    for (int j = 0; j < 8; ++j) {
      float x0 = sp[j], x1 = sp[8 + j];
      __bf16 a = (__bf16)x0, bb = (__bf16)x1;
      h0[j] = a; l0[j] = (__bf16)(x0 - (float)a);
      h1[j] = bb; l1[j] = (__bf16)(x1 - (float)bb);
    }
    int sw = (r & 7) << 4;
    int o0 = (r * 128 + cq * 32) ^ sw;
    int o1 = (r * 128 + cq * 32 + 16) ^ sw;
    *(bf16x8*)(dh + o0) = h0;
    *(bf16x8*)(dh + o1) = h1;
    *(bf16x8*)(dl + o0) = l0;
    *(bf16x8*)(dl + o1) = l1;
    return;
  }
  if (b < 2048) {
    b -= 1024;
    int kt = b & 15, h = b >> 4;
    const float* src = V + (size_t)h * 65536 + kt * 4096;
    char* dv = VT + (size_t)(h * 16 + kt) * 8192;
    int kp = threadIdx.x >> 3, dq = threadIdx.x & 7;
    const float* s0 = src + (2 * kp) * 64 + dq * 8;
    const float* s1 = s0 + 64;
#pragma unroll
    for (int j = 0; j < 8; ++j) {
      uint32 pk = pack_bf16(s0[j], s1[j]);
      int d = dq * 8 + j;
      *(uint32*)(dv + ((d * 128 + kp * 4) ^ ((d & 7) << 4))) = pk;
    }
    return;
  }
  // transposes
  const float* in;
  __bf16* out;
  int R, C, bx, by;
  if (b < 3072) {
    b -= 2048; in = Wf; out = WFT; R = 1024; C = 1024;
    bx = (b & 31) * 32; by = (b >> 5) * 32;
  } else if (b < 7168) {
    b -= 3072; in = W1; out = W1T; R = 1024; C = 4096;
    bx = (b & 127) * 32; by = (b >> 7) * 32;
  } else {
    b -= 7168; in = W2; out = W2T; R = 4096; C = 1024;
    bx = (b & 31) * 32; by = (b >> 5) * 32;
  }
  __shared__ float tile[32][33];
  int tx = threadIdx.x & 31, ty = threadIdx.x >> 5;
  for (int i = ty; i < 32; i += 8)
    tile[i][tx] = in[(size_t)(by + i) * C + bx + tx];
  __syncthreads();
  for (int i = ty; i < 32; i += 8)
    out[(size_t)(bx + i) * R + by + tx] = (__bf16)tile[tx][i];
}

// ---------------------------------------------------------------------------
// Attention v7: v6 + pass-1 ballot-gated deferred softmax reduction + setprio.
// Block = (head g, 128-row q block rb), 8 waves x 16 q rows.
// Q = v_input, K = k_input, V = q_input (reference signature quirk).
// ---------------------------------------------------------------------------
__global__ __launch_bounds__(512, 4) void attn_v7(
    const float* __restrict__ Qin, const char* __restrict__ KHimg,
    const char* __restrict__ KLimg, const char* __restrict__ VTimg,
    float* __restrict__ attn_out, __bf16* __restrict__ ctx_out)
{
  __shared__ __attribute__((aligned(16))) char KsH[2][8192];
  __shared__ __attribute__((aligned(16))) char KsL[2][8192];
  __shared__ __attribute__((aligned(16))) char Vt[2][8192];
  __shared__ __attribute__((aligned(16))) __bf16 PsH[8][16][72];

  const int tid = threadIdx.x;
  const int l = tid & 63, w = tid >> 6;
  const int lr = l & 15, q4 = l >> 4;
  const int swz = (blockIdx.x & 7) * 64 + (blockIdx.x >> 3);  // XCD chunking
  const int g = swz >> 3, rb = swz & 7;
  const size_t base = (size_t)g * 65536;
  const char* khb = KHimg + (size_t)g * 131072;
  const char* klb = KLimg + (size_t)g * 131072;
  const char* vtb = VTimg + (size_t)g * 131072;

  // Q fragments (per-lane row = rb*128 + w*16 + lr), split hi/lo
  const float* qp = Qin + base + (size_t)(rb * 128 + w * 16 + lr) * 64;
  f32x4 qv[4];
#pragma unroll
  for (int j = 0; j < 2; ++j) {
    qv[j] = *(const f32x4*)&qp[q4 * 8 + j * 4];
    qv[2 + j] = *(const f32x4*)&qp[32 + q4 * 8 + j * 4];
  }

  // stage pass-1 tile 0
  gld_lds16(khb + 0 * 8192 + tid * 16, (LDS_AS char*)&KsH[0][0] + tid * 16);
  gld_lds16(klb + 0 * 8192 + tid * 16, (LDS_AS char*)&KsL[0][0] + tid * 16);

  bf16x8 aqh0, aql0, aqh1, aql1;
#pragma unroll
  for (int j = 0; j < 8; ++j) {
    float x0 = qv[j >> 2][j & 3];
    float x1 = qv[2 + (j >> 2)][j & 3];
    __bf16 h0 = (__bf16)x0, h1 = (__bf16)x1;
    aqh0[j] = h0; aql0[j] = (__bf16)(x0 - (float)h0);
    aqh1[j] = h1; aql1[j] = (__bf16)(x1 - (float)h1);
  }

  float m_r[4], ll_r[4];
#pragma unroll
  for (int r = 0; r < 4; ++r) { m_r[r] = -1e30f; ll_r[r] = 0.f; }

  // ---- pass 1: stats (2 loads/tile, double-buffered) ----
  // Deferred-sum online softmax: per-lane partial l, ballot-gated max reduce.
  for (int kt = 0; kt < 16; ++kt) {
    const int buf = kt & 1;
    if (kt < 15) {
      gld_lds16(khb + (kt + 1) * 8192 + tid * 16,
                (LDS_AS char*)&KsH[buf ^ 1][0] + tid * 16);
      gld_lds16(klb + (kt + 1) * 8192 + tid * 16,
                (LDS_AS char*)&KsL[buf ^ 1][0] + tid * 16);
      asm volatile("s_waitcnt vmcnt(2)" ::: "memory");
    } else {
      asm volatile("s_waitcnt vmcnt(0)" ::: "memory");
    }
    __builtin_amdgcn_s_barrier();
    const char* ksh = KsH[buf];
    const char* ksl = KsL[buf];
    f32x4 c[4];
    __builtin_amdgcn_s_setprio(1);
#pragma unroll
    for (int nf = 0; nf < 4; ++nf) {
      int row = nf * 16 + lr;
      f32x4 cc = {0.f, 0.f, 0.f, 0.f};
      cc = mfma3(aqh0, aql0, *(const bf16x8*)(ksh + KB(row, q4 * 16)),
                 *(const bf16x8*)(ksl + KB(row, q4 * 16)), cc);
      cc = mfma3(aqh1, aql1, *(const bf16x8*)(ksh + KB(row, 64 + q4 * 16)),
                 *(const bf16x8*)(ksl + KB(row, 64 + q4 * 16)), cc);
      c[nf] = cc;
    }
    __builtin_amdgcn_s_setprio(0);
#pragma unroll
    for (int r = 0; r < 4; ++r) {
      float s0 = c[0][r] * 8.f, s1 = c[1][r] * 8.f;
      float s2 = c[2][r] * 8.f, s3 = c[3][r] * 8.f;
      float lm = fmaxf(fmaxf(s0, s1), fmaxf(s2, s3));
      // gate: does any lane of this 16-lane row-group exceed m+8?
      unsigned long long bal = __ballot(lm > m_r[r] + 8.f);
      if ((bal >> (q4 * 16)) & 0xFFFFull) {
        float tm = lm;
#pragma unroll
        for (int o = 1; o < 16; o <<= 1) tm = fmaxf(tm, __shfl_xor(tm, o, 64));
        float mnew = fmaxf(m_r[r], tm);
        ll_r[r] *= __expf(m_r[r] - mnew);
        m_r[r] = mnew;
      }
      ll_r[r] += __expf(s0 - m_r[r]) + __expf(s1 - m_r[r]) +
                 __expf(s2 - m_r[r]) + __expf(s3 - m_r[r]);
    }
    __builtin_amdgcn_s_barrier();
  }
  // final cross-lane sum reduce (once, not per tile)
  float inv_l[4];
#pragma unroll
  for (int r = 0; r < 4; ++r) {
    float se = ll_r[r];
#pragma unroll
    for (int o = 1; o < 16; o <<= 1) se += __shfl_xor(se, o, 64);
    inv_l[r] = 1.f / se;
  }

  f32x4 co[4];
#pragma unroll
  for (int cf = 0; cf < 4; ++cf) co[cf] = (f32x4){0.f, 0.f, 0.f, 0.f};

  // stage pass-2 tile 0 (K + V)
  gld_lds16(khb + 0 * 8192 + tid * 16, (LDS_AS char*)&KsH[0][0] + tid * 16);
  gld_lds16(klb + 0 * 8192 + tid * 16, (LDS_AS char*)&KsL[0][0] + tid * 16);
  gld_lds16(vtb + 0 * 8192 + tid * 16, (LDS_AS char*)&Vt[0][0] + tid * 16);

  // ---- pass 2: P (nt f32 attn out + bf16 Ps) + PV ----
  // vmcnt ledger per lane: 3 loads/STAGE, 16 attn stores/tile.
  for (int kt = 0; kt < 16; ++kt) {
    const int buf = kt & 1;
    if (kt < 15) {
      gld_lds16(khb + (kt + 1) * 8192 + tid * 16,
                (LDS_AS char*)&KsH[buf ^ 1][0] + tid * 16);
      gld_lds16(klb + (kt + 1) * 8192 + tid * 16,
                (LDS_AS char*)&KsL[buf ^ 1][0] + tid * 16);
      gld_lds16(vtb + (kt + 1) * 8192 + tid * 16,
                (LDS_AS char*)&Vt[buf ^ 1][0] + tid * 16);
    }
    if (kt == 0) {
      asm volatile("s_waitcnt vmcnt(3)" ::: "memory");
    } else if (kt < 15) {
      asm volatile("s_waitcnt vmcnt(19)" ::: "memory");
    } else {
      asm volatile("s_waitcnt vmcnt(16)" ::: "memory");
    }
    __builtin_amdgcn_s_barrier();
    const char* ksh = KsH[buf];
    const char* ksl = KsL[buf];
    const char* vts = Vt[buf];
#pragma unroll
    for (int nf = 0; nf < 4; ++nf) {
      int row = nf * 16 + lr;
      f32x4 cc = {0.f, 0.f, 0.f, 0.f};
      __builtin_amdgcn_s_setprio(1);
      cc = mfma3(aqh0, aql0, *(const bf16x8*)(ksh + KB(row, q4 * 16)),
                 *(const bf16x8*)(ksl + KB(row, q4 * 16)), cc);
      cc = mfma3(aqh1, aql1, *(const bf16x8*)(ksh + KB(row, 64 + q4 * 16)),
                 *(const bf16x8*)(ksl + KB(row, 64 + q4 * 16)), cc);
      __builtin_amdgcn_s_setprio(0);
#pragma unroll
      for (int r = 0; r < 4; ++r) {
        float p = __expf(cc[r] * 8.f - m_r[r]) * inv_l[r];
        PsH[w][q4 * 4 + r][nf * 16 + lr] = (__bf16)p;
        int arow = rb * 128 + w * 16 + q4 * 4 + r;
        __builtin_nontemporal_store(
            p, &attn_out[((size_t)(g * 1024 + arow)) * 1024 + kt * 64 + nf * 16 + lr]);
      }
    }
    // PV: PsH[w] same-wave; Vt[buf] staged this tile
    __builtin_amdgcn_s_setprio(1);
#pragma unroll
    for (int kk = 0; kk < 2; ++kk) {
      bf16x8 ph = *(const bf16x8*)&PsH[w][lr][kk * 32 + q4 * 8];
#pragma unroll
      for (int cf = 0; cf < 4; ++cf) {
        bf16x8 vt = *(const bf16x8*)(vts + KB(cf * 16 + lr, kk * 64 + q4 * 16));
        co[cf] = MFMA(ph, vt, co[cf]);
      }
    }
    __builtin_amdgcn_s_setprio(0);
    __builtin_amdgcn_s_barrier();
  }
#pragma unroll
  for (int cf = 0; cf < 4; ++cf)
#pragma unroll
    for (int r = 0; r < 4; ++r) {
      int i = rb * 128 + w * 16 + q4 * 4 + r;
      ctx_out[((size_t)(g * 1024 + i)) * 64 + cf * 16 + lr] = (__bf16)co[cf][r];
    }
}

// ---------------------------------------------------------------------------
// m97-structure bf16 GEMM: C = A[MxK] * Bt[NxK]^T (+bias) (+Res).
// Tile BM x 128, 4 waves, 1D grid with XCD-chunked swizzle.
// EPI 0: Outf = acc+bias+Res(f32). EPI 1: Outb = bf16(relu(acc+bias)) [nt].
// EPI 2: Outf = acc+bias+ResB(bf16). EPI 3: Outf = acc (pure partial).
// Kloop = #K elements this block accumulates (stride stays K).
// ---------------------------------------------------------------------------
template <int EPI, int BM>
__global__ __launch_bounds__(256) void gemm_bt(
    const __bf16* __restrict__ A, const __bf16* __restrict__ Bt,
    const float* __restrict__ bias, const float* __restrict__ Res,
    const __bf16* __restrict__ ResB, float* __restrict__ Outf,
    __bf16* __restrict__ Outb, int M, int N, int K, int Kloop, int nbx,
    int tiles_per_out)
{
  constexpr int MF = BM / 32;
  __shared__ __attribute__((aligned(16))) __bf16 sm[BM * 64 + 8192];
  const int tid = threadIdx.x;
  const int l = tid & 63, w = tid >> 6;
  const int lr = l & 15, lkb = (l >> 4) * 8;
  const int nwg = gridDim.x;
  const int swz = (blockIdx.x & 7) * (nwg >> 3) + (blockIdx.x >> 3);
  const int ks = swz / tiles_per_out;          // split-K slice
  const int tile = swz % tiles_per_out;
  const int m0 = (tile / nbx) * BM, n0 = (tile % nbx) * 128;
  const int kbase = ks * Kloop;
  const int wr = (w >> 1) * (BM / 2), wc = (w & 1) * 64;
  LDS_AS char* sm3 = (LDS_AS char*)sm;

  f32x4 acc[MF][4];
  f32x4 zero = {0.f, 0.f, 0.f, 0.f};
#pragma unroll
  for (int m = 0; m < MF; ++m)
#pragma unroll
    for (int n = 0; n < 4; ++n) acc[m][n] = zero;

  const int nkt = Kloop >> 6;
  for (int kt = 0; kt < nkt; ++kt) {
    __syncthreads();
#pragma unroll
    for (int it = 0; it < MF; ++it) {
      int slot = it * 256 + tid;
      int row = slot >> 3, cb = slot & 7;
      gld_lds16(&A[(size_t)(m0 + row) * K + kbase + kt * 64 + cb * 8],
                sm3 + slot * 16);
    }
#pragma unroll
    for (int it = 0; it < 4; ++it) {
      int slot = it * 256 + tid;
      int row = slot >> 3, cb = slot & 7;
      gld_lds16(&Bt[(size_t)(n0 + row) * K + kbase + kt * 64 + cb * 8],
                sm3 + BM * 128 + slot * 16);
    }
    __syncthreads();
#pragma unroll
    for (int kk = 0; kk < 2; ++kk) {
      bf16x8 a[MF], b[4];
#pragma unroll
      for (int m = 0; m < MF; ++m)
        a[m] = *(const bf16x8*)&sm[(wr + m * 16 + lr) * 64 + kk * 32 + lkb];
#pragma unroll
      for (int n = 0; n < 4; ++n)
        b[n] = *(const bf16x8*)&sm[BM * 64 + (wc + n * 16 + lr) * 64 + kk * 32 + lkb];
#pragma unroll
      for (int m = 0; m < MF; ++m)
#pragma unroll
        for (int n = 0; n < 4; ++n) acc[m][n] = MFMA(a[m], b[n], acc[m][n]);
    }
  }

  float* outp = (EPI == 3) ? Outf + (size_t)ks * M * N : Outf;
#pragma unroll
  for (int n = 0; n < 4; ++n) {
    int gcol = n0 + wc + n * 16 + lr;
    float bc = (EPI == 3) ? 0.f : bias[gcol];
#pragma unroll
    for (int m = 0; m < MF; ++m) {
      int grow = m0 + wr + m * 16 + (l >> 4) * 4;
#pragma unroll
      for (int r = 0; r < 4; ++r) {
        float v = acc[m][n][r] + bc;
        size_t o = (size_t)(grow + r) * N + gcol;
        if (EPI == 1) {
          __builtin_nontemporal_store((__bf16)fmaxf(v, 0.f), &Outb[o]);
        } else if (EPI == 0) {
          outp[o] = v + Res[o];
        } else if (EPI == 2) {
          outp[o] = v + (float)ResB[o];
        } else {
          outp[o] = v;
        }
      }
    }
  }
}

// ---------------------------------------------------------------------------
// LayerNorm over D=1024, one block per row. OUTF: f32 out; OUTB: bf16 out.
// ---------------------------------------------------------------------------
template <int OUTF, int OUTB>
__global__ __launch_bounds__(256) void ln_kernel(
    const float* __restrict__ in, const float* __restrict__ gam,
    const float* __restrict__ bet, float* __restrict__ out,
    __bf16* __restrict__ outB)
{
  __shared__ float red[8];
  const int row = blockIdx.x, t = threadIdx.x;
  const float* rp = in + (size_t)row * 1024;
  f32x4 v = ((const f32x4*)rp)[t];
  float s = 0.f, ss = 0.f;
#pragma unroll
  for (int j = 0; j < 4; ++j) {
    s += v[j];
    ss += v[j] * v[j];
  }
#pragma unroll
  for (int o = 1; o < 64; o <<= 1) {
    s += __shfl_xor(s, o, 64);
    ss += __shfl_xor(ss, o, 64);
  }
  int w = t >> 6, l = t & 63;
  if (l == 0) { red[w] = s; red[4 + w] = ss; }
  __syncthreads();
  float S = red[0] + red[1] + red[2] + red[3];
  float SS = red[4] + red[5] + red[6] + red[7];
  float mean = S * (1.f / 1024.f);
  float var = SS * (1.f / 1024.f) - mean * mean;
  float rstd = rsqrtf(var + 1e-5f);
  f32x4 ov;
#pragma unroll
  for (int j = 0; j < 4; ++j) {
    int col = t * 4 + j;
    ov[j] = (v[j] - mean) * rstd * gam[col] + bet[col];
  }
  if (OUTF) ((f32x4*)(out + (size_t)row * 1024))[t] = ov;
  if (OUTB) {
    bf16x4 ob;
#pragma unroll
    for (int j = 0; j < 4; ++j) ob[j] = (__bf16)ov[j];
    *(bf16x4*)&outB[(size_t)row * 1024 + t * 4] = ob;
  }
}

// ---------------------------------------------------------------------------
// Fused final LN: x = P0 + P1 + bias + resB (bf16), out = LN(x)*g + b (f32)
// ---------------------------------------------------------------------------
__global__ __launch_bounds__(256) void ln_fuse2(
    const float* __restrict__ P0, const float* __restrict__ P1,
    const float* __restrict__ bias, const __bf16* __restrict__ resB,
    const float* __restrict__ gam, const float* __restrict__ bet,
    float* __restrict__ out)
{
  __shared__ float red[8];
  const int row = blockIdx.x, t = threadIdx.x;
  const size_t ro = (size_t)row * 1024;
  f32x4 v = ((const f32x4*)(P0 + ro))[t];
  f32x4 v1 = ((const f32x4*)(P1 + ro))[t];
  f32x4 bi = ((const f32x4*)bias)[t];
  bf16x4 rb = ((const bf16x4*)(resB + ro))[t];
  float s = 0.f, ss = 0.f;
#pragma unroll
  for (int j = 0; j < 4; ++j) {
    v[j] = v[j] + v1[j] + bi[j] + (float)rb[j];
    s += v[j];
    ss += v[j] * v[j];
  }
#pragma unroll
  for (int o = 1; o < 64; o <<= 1) {
    s += __shfl_xor(s, o, 64);
    ss += __shfl_xor(ss, o, 64);
  }
  int w = t >> 6, l = t & 63;
  if (l == 0) { red[w] = s; red[4 + w] = ss; }
  __syncthreads();
  float S = red[0] + red[1] + red[2] + red[3];
  float SS = red[4] + red[5] + red[6] + red[7];
  float mean = S * (1.f / 1024.f);
  float var = SS * (1.f / 1024.f) - mean * mean;
  float rstd = rsqrtf(var + 1e-5f);
  f32x4 ov;
#pragma unroll
  for (int j = 0; j < 4; ++j) {
    int col = t * 4 + j;
    ov[j] = (v[j] - mean) * rstd * gam[col] + bet[col];
  }
  ((f32x4*)(out + ro))[t] = ov;
}

// ---------------------------------------------------------------------------
extern "C" void kernel_launch(void* const* d_in, const int* in_sizes, int n_in,
                              void* d_out, int out_size, void* d_ws, size_t ws_size,
                              hipStream_t stream) {
  const float* k_in = (const float*)d_in[0];
  const float* v_in = (const float*)d_in[1];
  const float* q_in = (const float*)d_in[2];
  const float* r_in = (const float*)d_in[3];
  const float* Wf = (const float*)d_in[4];
  const float* bf = (const float*)d_in[5];
  const float* g1 = (const float*)d_in[6];
  const float* b1 = (const float*)d_in[7];
  const float* W1 = (const float*)d_in[8];
  const float* bw1 = (const float*)d_in[9];
  const float* W2 = (const float*)d_in[10];
  const float* bw2 = (const float*)d_in[11];
  const float* g2 = (const float*)d_in[12];
  const float* b2 = (const float*)d_in[13];

  float* out0 = (float*)d_out;          // [4096,1024]
  float* attn = out0 + 4194304;         // [64,1024,1024]

  char* W = (char*)d_ws;
  const size_t MB = 1024 * 1024;
  char* KHimg = W + 0;                   // 8MB
  char* KLimg = W + 8 * MB;              // 8MB
  char* VTimg = W + 16 * MB;             // 8MB
  __bf16* WFT = (__bf16*)(W + 24 * MB);  // 2MB
  __bf16* W1T = (__bf16*)(W + 26 * MB);  // 8MB
  __bf16* W2T = (__bf16*)(W + 34 * MB);  // 8MB
  __bf16* CTX = (__bf16*)(W + 42 * MB);  // 8MB
  __bf16* Xb = (__bf16*)(W + 50 * MB);   // 8MB
  __bf16* Hb = (__bf16*)(W + 58 * MB);   // 32MB
  float* T1 = (float*)(W + 90 * MB);     // 16MB
  float* P0 = (float*)(W + 106 * MB);    // 16MB split-K partial 0
  float* P1 = (float*)(W + 122 * MB);    // 16MB split-K partial 1

  prep_all<<<11264, 256, 0, stream>>>(k_in, q_in, KHimg, KLimg, VTimg,
                                      Wf, WFT, W1, W1T, W2, W2T);

  attn_v7<<<512, 512, 0, stream>>>(v_in, KHimg, KLimg, VTimg, attn, CTX);

  // t1 = r + ctx @ Wf + bf
  gemm_bt<0, 64><<<512, 256, 0, stream>>>(CTX, WFT, bf, r_in, nullptr, T1,
                                          nullptr, 4096, 1024, 1024, 1024, 8, 512);
  // x = LN(t1) -> bf16 only
  ln_kernel<0, 1><<<4096, 256, 0, stream>>>(T1, g1, b1, nullptr, Xb);
  // h = relu(x @ W1 + bw1) -> bf16 (nt store)
  gemm_bt<1, 128><<<1024, 256, 0, stream>>>(Xb, W1T, bw1, nullptr, nullptr,
                                            nullptr, Hb, 4096, 4096, 1024, 1024,
                                            32, 1024);
  // split-K=2 partials of h @ W2  (BM=128, 256 tiles x 2 slices)
  gemm_bt<3, 128><<<512, 256, 0, stream>>>(Hb, W2T, nullptr, nullptr, nullptr,
                                           P0, nullptr, 4096, 1024, 4096, 2048,
                                           8, 256);
  // out = LN(P0 + P1 + bw2 + x)
  ln_fuse2<<<4096, 256, 0, stream>>>(P0, P1, bw2, Xb, g2, b2, out0);
}

// Round 9
// 298.002 us; speedup vs baseline: 1.1026x; 1.1026x over previous
//
#include <hip/hip_runtime.h>
#include <hip/hip_bf16.h>
#include <cstdint>

typedef __attribute__((ext_vector_type(8))) __bf16 bf16x8;
typedef __attribute__((ext_vector_type(4))) __bf16 bf16x4;
typedef __attribute__((ext_vector_type(4))) float f32x4;
typedef unsigned int uint32;
typedef unsigned short uint16;

#define LDS_AS __attribute__((address_space(3)))
#define GLB_AS __attribute__((address_space(1)))

static __device__ __forceinline__ void gld_lds16(const void* g, LDS_AS char* l) {
  __builtin_amdgcn_global_load_lds((const GLB_AS uint32*)g, (LDS_AS uint32*)l, 16, 0, 0);
}

#define MFMA(a, b, c) __builtin_amdgcn_mfma_f32_16x16x32_bf16((a), (b), (c), 0, 0, 0)

// 3-term split-bf16 MFMA: A*B ~= Ah*Bh + Al*Bh + Ah*Bl
static __device__ __forceinline__ f32x4 mfma3(bf16x8 ah, bf16x8 al, bf16x8 bh,
                                              bf16x8 bl, f32x4 c) {
  c = MFMA(ah, bh, c);
  c = MFMA(al, bh, c);
  c = MFMA(ah, bl, c);
  return c;
}

static __device__ __forceinline__ uint32 pack_bf16(float a, float b) {
  __bf16 ha = (__bf16)a, hb = (__bf16)b;
  return (uint32)__builtin_bit_cast(uint16, ha) |
         ((uint32)__builtin_bit_cast(uint16, hb) << 16);
}

// XOR swizzle: spreads stride-128B rows across banks (T2, rule #21 both-sides)
#define KB(row, colbyte) ((((row) * 128 + (colbyte))) ^ (((row) & 7) << 4))

// ---------------------------------------------------------------------------
// prep_all: one dispatch for all input preprocessing.
//  blocks 0..1023     : K f32 -> split bf16 hi/lo swizzled images KH/KL
//  blocks 1024..2047  : V f32 -> V^T swizzled image, k-pairs packed u32
//  blocks 2048..3071  : Wf  transpose -> bf16 WFT  [1024x1024]
//  blocks 3072..7167  : W1  transpose -> bf16 W1T  [4096x1024]
//  blocks 7168..11263 : W2  transpose -> bf16 W2T  [1024x4096]
// ---------------------------------------------------------------------------
__global__ __launch_bounds__(256) void prep_all(
    const float* __restrict__ K, const float* __restrict__ V,
    char* __restrict__ KH, char* __restrict__ KL, char* __restrict__ VT,
    const float* __restrict__ Wf, __bf16* __restrict__ WFT,
    const float* __restrict__ W1, __bf16* __restrict__ W1T,
    const float* __restrict__ W2, __bf16* __restrict__ W2T) {
  int b = blockIdx.x;
  if (b < 1024) {
    int kt = b & 15, h = b >> 4;
    const float* src = K + (size_t)h * 65536 + kt * 4096;
    char* dh = KH + (size_t)(h * 16 + kt) * 8192;
    char* dl = KL + (size_t)(h * 16 + kt) * 8192;
    int r = threadIdx.x >> 2, cq = threadIdx.x & 3;
    const float* sp = src + r * 64 + cq * 16;
    bf16x8 h0, l0, h1, l1;
#pragma unroll
    for (int j = 0; j < 8; ++j) {
      float x0 = sp[j], x1 = sp[8 + j];
      __bf16 a = (__bf16)x0, bb = (__bf16)x1;
      h0[j] = a; l0[j] = (__bf16)(x0 - (float)a);
      h1[j] = bb; l1[j] = (__bf16)(x1 - (float)bb);
    }
    int sw = (r & 7) << 4;
    int o0 = (r * 128 + cq * 32) ^ sw;
    int o1 = (r * 128 + cq * 32 + 16) ^ sw;
    *(bf16x8*)(dh + o0) = h0;
    *(bf16x8*)(dh + o1) = h1;
    *(bf16x8*)(dl + o0) = l0;
    *(bf16x8*)(dl + o1) = l1;
    return;
  }
  if (b < 2048) {
    b -= 1024;
    int kt = b & 15, h = b >> 4;
    const float* src = V + (size_t)h * 65536 + kt * 4096;
    char* dv = VT + (size_t)(h * 16 + kt) * 8192;
    int kp = threadIdx.x >> 3, dq = threadIdx.x & 7;
    const float* s0 = src + (2 * kp) * 64 + dq * 8;
    const float* s1 = s0 + 64;
#pragma unroll
    for (int j = 0; j < 8; ++j) {
      uint32 pk = pack_bf16(s0[j], s1[j]);
      int d = dq * 8 + j;
      *(uint32*)(dv + ((d * 128 + kp * 4) ^ ((d & 7) << 4))) = pk;
    }
    return;
  }
  // transposes
  const float* in;
  __bf16* out;
  int R, C, bx, by;
  if (b < 3072) {
    b -= 2048; in = Wf; out = WFT; R = 1024; C = 1024;
    bx = (b & 31) * 32; by = (b >> 5) * 32;
  } else if (b < 7168) {
    b -= 3072; in = W1; out = W1T; R = 1024; C = 4096;
    bx = (b & 127) * 32; by = (b >> 7) * 32;
  } else {
    b -= 7168; in = W2; out = W2T; R = 4096; C = 1024;
    bx = (b & 31) * 32; by = (b >> 5) * 32;
  }
  __shared__ float tile[32][33];
  int tx = threadIdx.x & 31, ty = threadIdx.x >> 5;
  for (int i = ty; i < 32; i += 8)
    tile[i][tx] = in[(size_t)(by + i) * C + bx + tx];
  __syncthreads();
  for (int i = ty; i < 32; i += 8)
    out[(size_t)(bx + i) * R + by + tx] = (__bf16)tile[tx][i];
}

// ---------------------------------------------------------------------------
// Attention v8: round-7 structure + fully lane-local pass-1 online softmax
// (zero cross-lane ops in the k-loop; single 16-lane combine at the end).
// No setprio (m190 regime evidence). nt only on the never-re-read P store.
// Block = (head g, 128-row q block rb), 8 waves x 16 q rows.
// Q = v_input, K = k_input, V = q_input (reference signature quirk).
// ---------------------------------------------------------------------------
__global__ __launch_bounds__(512, 4) void attn_v8(
    const float* __restrict__ Qin, const char* __restrict__ KHimg,
    const char* __restrict__ KLimg, const char* __restrict__ VTimg,
    float* __restrict__ attn_out, __bf16* __restrict__ ctx_out)
{
  __shared__ __attribute__((aligned(16))) char KsH[2][8192];
  __shared__ __attribute__((aligned(16))) char KsL[2][8192];
  __shared__ __attribute__((aligned(16))) char Vt[2][8192];
  __shared__ __attribute__((aligned(16))) __bf16 PsH[8][16][72];

  const int tid = threadIdx.x;
  const int l = tid & 63, w = tid >> 6;
  const int lr = l & 15, q4 = l >> 4;
  const int swz = (blockIdx.x & 7) * 64 + (blockIdx.x >> 3);  // XCD chunking
  const int g = swz >> 3, rb = swz & 7;
  const size_t base = (size_t)g * 65536;
  const char* khb = KHimg + (size_t)g * 131072;
  const char* klb = KLimg + (size_t)g * 131072;
  const char* vtb = VTimg + (size_t)g * 131072;

  // Q fragments (per-lane row = rb*128 + w*16 + lr), split hi/lo
  const float* qp = Qin + base + (size_t)(rb * 128 + w * 16 + lr) * 64;
  f32x4 qv[4];
#pragma unroll
  for (int j = 0; j < 2; ++j) {
    qv[j] = *(const f32x4*)&qp[q4 * 8 + j * 4];
    qv[2 + j] = *(const f32x4*)&qp[32 + q4 * 8 + j * 4];
  }

  // stage pass-1 tile 0
  gld_lds16(khb + 0 * 8192 + tid * 16, (LDS_AS char*)&KsH[0][0] + tid * 16);
  gld_lds16(klb + 0 * 8192 + tid * 16, (LDS_AS char*)&KsL[0][0] + tid * 16);

  bf16x8 aqh0, aql0, aqh1, aql1;
#pragma unroll
  for (int j = 0; j < 8; ++j) {
    float x0 = qv[j >> 2][j & 3];
    float x1 = qv[2 + (j >> 2)][j & 3];
    __bf16 h0 = (__bf16)x0, h1 = (__bf16)x1;
    aqh0[j] = h0; aql0[j] = (__bf16)(x0 - (float)h0);
    aqh1[j] = h1; aql1[j] = (__bf16)(x1 - (float)h1);
  }

  // lane-local online stats: m_r/ll_r cover only this lane's 4 cols per nf
  float m_r[4], ll_r[4];
#pragma unroll
  for (int r = 0; r < 4; ++r) { m_r[r] = -1e30f; ll_r[r] = 0.f; }

  // ---- pass 1: stats (2 loads/tile, double-buffered, zero shfl in loop) ----
  for (int kt = 0; kt < 16; ++kt) {
    const int buf = kt & 1;
    if (kt < 15) {
      gld_lds16(khb + (kt + 1) * 8192 + tid * 16,
                (LDS_AS char*)&KsH[buf ^ 1][0] + tid * 16);
      gld_lds16(klb + (kt + 1) * 8192 + tid * 16,
                (LDS_AS char*)&KsL[buf ^ 1][0] + tid * 16);
      asm volatile("s_waitcnt vmcnt(2)" ::: "memory");
    } else {
      asm volatile("s_waitcnt vmcnt(0)" ::: "memory");
    }
    __builtin_amdgcn_s_barrier();
    const char* ksh = KsH[buf];
    const char* ksl = KsL[buf];
    f32x4 c[4];
#pragma unroll
    for (int nf = 0; nf < 4; ++nf) {
      int row = nf * 16 + lr;
      f32x4 cc = {0.f, 0.f, 0.f, 0.f};
      cc = mfma3(aqh0, aql0, *(const bf16x8*)(ksh + KB(row, q4 * 16)),
                 *(const bf16x8*)(ksl + KB(row, q4 * 16)), cc);
      cc = mfma3(aqh1, aql1, *(const bf16x8*)(ksh + KB(row, 64 + q4 * 16)),
                 *(const bf16x8*)(ksl + KB(row, 64 + q4 * 16)), cc);
      c[nf] = cc;
    }
#pragma unroll
    for (int r = 0; r < 4; ++r) {
      float s0 = c[0][r] * 8.f, s1 = c[1][r] * 8.f;
      float s2 = c[2][r] * 8.f, s3 = c[3][r] * 8.f;
      float lm = fmaxf(fmaxf(s0, s1), fmaxf(s2, s3));
      float mnew = fmaxf(m_r[r], lm);
      ll_r[r] = ll_r[r] * __expf(m_r[r] - mnew) +
                (__expf(s0 - mnew) + __expf(s1 - mnew) +
                 __expf(s2 - mnew) + __expf(s3 - mnew));
      m_r[r] = mnew;
    }
    __builtin_amdgcn_s_barrier();
  }
  // single cross-lane combine: M = max over 16 lanes, l = sum ll*exp(m-M)
  float inv_l[4];
#pragma unroll
  for (int r = 0; r < 4; ++r) {
    float M = m_r[r];
#pragma unroll
    for (int o = 1; o < 16; o <<= 1) M = fmaxf(M, __shfl_xor(M, o, 64));
    float ls = ll_r[r] * __expf(m_r[r] - M);
#pragma unroll
    for (int o = 1; o < 16; o <<= 1) ls += __shfl_xor(ls, o, 64);
    m_r[r] = M;
    inv_l[r] = 1.f / ls;
  }

  f32x4 co[4];
#pragma unroll
  for (int cf = 0; cf < 4; ++cf) co[cf] = (f32x4){0.f, 0.f, 0.f, 0.f};

  // stage pass-2 tile 0 (K + V)
  gld_lds16(khb + 0 * 8192 + tid * 16, (LDS_AS char*)&KsH[0][0] + tid * 16);
  gld_lds16(klb + 0 * 8192 + tid * 16, (LDS_AS char*)&KsL[0][0] + tid * 16);
  gld_lds16(vtb + 0 * 8192 + tid * 16, (LDS_AS char*)&Vt[0][0] + tid * 16);

  // ---- pass 2: P (nt f32 attn out + bf16 Ps) + PV ----
  // vmcnt ledger per lane: 3 loads/STAGE, 16 attn stores/tile.
  for (int kt = 0; kt < 16; ++kt) {
    const int buf = kt & 1;
    if (kt < 15) {
      gld_lds16(khb + (kt + 1) * 8192 + tid * 16,
                (LDS_AS char*)&KsH[buf ^ 1][0] + tid * 16);
      gld_lds16(klb + (kt + 1) * 8192 + tid * 16,
                (LDS_AS char*)&KsL[buf ^ 1][0] + tid * 16);
      gld_lds16(vtb + (kt + 1) * 8192 + tid * 16,
                (LDS_AS char*)&Vt[buf ^ 1][0] + tid * 16);
    }
    if (kt == 0) {
      asm volatile("s_waitcnt vmcnt(3)" ::: "memory");
    } else if (kt < 15) {
      asm volatile("s_waitcnt vmcnt(19)" ::: "memory");
    } else {
      asm volatile("s_waitcnt vmcnt(16)" ::: "memory");
    }
    __builtin_amdgcn_s_barrier();
    const char* ksh = KsH[buf];
    const char* ksl = KsL[buf];
    const char* vts = Vt[buf];
#pragma unroll
    for (int nf = 0; nf < 4; ++nf) {
      int row = nf * 16 + lr;
      f32x4 cc = {0.f, 0.f, 0.f, 0.f};
      cc = mfma3(aqh0, aql0, *(const bf16x8*)(ksh + KB(row, q4 * 16)),
                 *(const bf16x8*)(ksl + KB(row, q4 * 16)), cc);
      cc = mfma3(aqh1, aql1, *(const bf16x8*)(ksh + KB(row, 64 + q4 * 16)),
                 *(const bf16x8*)(ksl + KB(row, 64 + q4 * 16)), cc);
#pragma unroll
      for (int r = 0; r < 4; ++r) {
        float p = __expf(cc[r] * 8.f - m_r[r]) * inv_l[r];
        PsH[w][q4 * 4 + r][nf * 16 + lr] = (__bf16)p;
        int arow = rb * 128 + w * 16 + q4 * 4 + r;
        __builtin_nontemporal_store(
            p, &attn_out[((size_t)(g * 1024 + arow)) * 1024 + kt * 64 + nf * 16 + lr]);
      }
    }
    // PV: PsH[w] same-wave; Vt[buf] staged this tile
#pragma unroll
    for (int kk = 0; kk < 2; ++kk) {
      bf16x8 ph = *(const bf16x8*)&PsH[w][lr][kk * 32 + q4 * 8];
#pragma unroll
      for (int cf = 0; cf < 4; ++cf) {
        bf16x8 vt = *(const bf16x8*)(vts + KB(cf * 16 + lr, kk * 64 + q4 * 16));
        co[cf] = MFMA(ph, vt, co[cf]);
      }
    }
    __builtin_amdgcn_s_barrier();
  }
#pragma unroll
  for (int cf = 0; cf < 4; ++cf)
#pragma unroll
    for (int r = 0; r < 4; ++r) {
      int i = rb * 128 + w * 16 + q4 * 4 + r;
      ctx_out[((size_t)(g * 1024 + i)) * 64 + cf * 16 + lr] = (__bf16)co[cf][r];
    }
}

// ---------------------------------------------------------------------------
// m97-structure bf16 GEMM: C = A[MxK] * Bt[NxK]^T (+bias) (+Res).
// Tile BM x 128, 4 waves, 1D grid with XCD-chunked swizzle.
// EPI 0: Outf = acc+bias+Res(f32). EPI 1: Outb = bf16(relu(acc+bias)).
// EPI 2: Outf = acc+bias+ResB(bf16). EPI 3: Outf = acc (pure partial).
// Kloop = #K elements this block accumulates (stride stays K).
// ---------------------------------------------------------------------------
template <int EPI, int BM>
__global__ __launch_bounds__(256) void gemm_bt(
    const __bf16* __restrict__ A, const __bf16* __restrict__ Bt,
    const float* __restrict__ bias, const float* __restrict__ Res,
    const __bf16* __restrict__ ResB, float* __restrict__ Outf,
    __bf16* __restrict__ Outb, int M, int N, int K, int Kloop, int nbx,
    int tiles_per_out)
{
  constexpr int MF = BM / 32;
  __shared__ __attribute__((aligned(16))) __bf16 sm[BM * 64 + 8192];
  const int tid = threadIdx.x;
  const int l = tid & 63, w = tid >> 6;
  const int lr = l & 15, lkb = (l >> 4) * 8;
  const int nwg = gridDim.x;
  const int swz = (blockIdx.x & 7) * (nwg >> 3) + (blockIdx.x >> 3);
  const int ks = swz / tiles_per_out;          // split-K slice
  const int tile = swz % tiles_per_out;
  const int m0 = (tile / nbx) * BM, n0 = (tile % nbx) * 128;
  const int kbase = ks * Kloop;
  const int wr = (w >> 1) * (BM / 2), wc = (w & 1) * 64;
  LDS_AS char* sm3 = (LDS_AS char*)sm;

  f32x4 acc[MF][4];
  f32x4 zero = {0.f, 0.f, 0.f, 0.f};
#pragma unroll
  for (int m = 0; m < MF; ++m)
#pragma unroll
    for (int n = 0; n < 4; ++n) acc[m][n] = zero;

  const int nkt = Kloop >> 6;
  for (int kt = 0; kt < nkt; ++kt) {
    __syncthreads();
#pragma unroll
    for (int it = 0; it < MF; ++it) {
      int slot = it * 256 + tid;
      int row = slot >> 3, cb = slot & 7;
      gld_lds16(&A[(size_t)(m0 + row) * K + kbase + kt * 64 + cb * 8],
                sm3 + slot * 16);
    }
#pragma unroll
    for (int it = 0; it < 4; ++it) {
      int slot = it * 256 + tid;
      int row = slot >> 3, cb = slot & 7;
      gld_lds16(&Bt[(size_t)(n0 + row) * K + kbase + kt * 64 + cb * 8],
                sm3 + BM * 128 + slot * 16);
    }
    __syncthreads();
#pragma unroll
    for (int kk = 0; kk < 2; ++kk) {
      bf16x8 a[MF], b[4];
#pragma unroll
      for (int m = 0; m < MF; ++m)
        a[m] = *(const bf16x8*)&sm[(wr + m * 16 + lr) * 64 + kk * 32 + lkb];
#pragma unroll
      for (int n = 0; n < 4; ++n)
        b[n] = *(const bf16x8*)&sm[BM * 64 + (wc + n * 16 + lr) * 64 + kk * 32 + lkb];
#pragma unroll
      for (int m = 0; m < MF; ++m)
#pragma unroll
        for (int n = 0; n < 4; ++n) acc[m][n] = MFMA(a[m], b[n], acc[m][n]);
    }
  }

  float* outp = (EPI == 3) ? Outf + (size_t)ks * M * N : Outf;
#pragma unroll
  for (int n = 0; n < 4; ++n) {
    int gcol = n0 + wc + n * 16 + lr;
    float bc = (EPI == 3) ? 0.f : bias[gcol];
#pragma unroll
    for (int m = 0; m < MF; ++m) {
      int grow = m0 + wr + m * 16 + (l >> 4) * 4;
#pragma unroll
      for (int r = 0; r < 4; ++r) {
        float v = acc[m][n][r] + bc;
        size_t o = (size_t)(grow + r) * N + gcol;
        if (EPI == 1) {
          Outb[o] = (__bf16)fmaxf(v, 0.f);
        } else if (EPI == 0) {
          outp[o] = v + Res[o];
        } else if (EPI == 2) {
          outp[o] = v + (float)ResB[o];
        } else {
          outp[o] = v;
        }
      }
    }
  }
}

// ---------------------------------------------------------------------------
// LayerNorm over D=1024, one block per row. OUTF: f32 out; OUTB: bf16 out.
// ---------------------------------------------------------------------------
template <int OUTF, int OUTB>
__global__ __launch_bounds__(256) void ln_kernel(
    const float* __restrict__ in, const float* __restrict__ gam,
    const float* __restrict__ bet, float* __restrict__ out,
    __bf16* __restrict__ outB)
{
  __shared__ float red[8];
  const int row = blockIdx.x, t = threadIdx.x;
  const float* rp = in + (size_t)row * 1024;
  f32x4 v = ((const f32x4*)rp)[t];
  float s = 0.f, ss = 0.f;
#pragma unroll
  for (int j = 0; j < 4; ++j) {
    s += v[j];
    ss += v[j] * v[j];
  }
#pragma unroll
  for (int o = 1; o < 64; o <<= 1) {
    s += __shfl_xor(s, o, 64);
    ss += __shfl_xor(ss, o, 64);
  }
  int w = t >> 6, l = t & 63;
  if (l == 0) { red[w] = s; red[4 + w] = ss; }
  __syncthreads();
  float S = red[0] + red[1] + red[2] + red[3];
  float SS = red[4] + red[5] + red[6] + red[7];
  float mean = S * (1.f / 1024.f);
  float var = SS * (1.f / 1024.f) - mean * mean;
  float rstd = rsqrtf(var + 1e-5f);
  f32x4 ov;
#pragma unroll
  for (int j = 0; j < 4; ++j) {
    int col = t * 4 + j;
    ov[j] = (v[j] - mean) * rstd * gam[col] + bet[col];
  }
  if (OUTF) ((f32x4*)(out + (size_t)row * 1024))[t] = ov;
  if (OUTB) {
    bf16x4 ob;
#pragma unroll
    for (int j = 0; j < 4; ++j) ob[j] = (__bf16)ov[j];
    *(bf16x4*)&outB[(size_t)row * 1024 + t * 4] = ob;
  }
}

// ---------------------------------------------------------------------------
// Fused final LN: x = P0 + P1 + bias + resB (bf16), out = LN(x)*g + b (f32)
// ---------------------------------------------------------------------------
__global__ __launch_bounds__(256) void ln_fuse2(
    const float* __restrict__ P0, const float* __restrict__ P1,
    const float* __restrict__ bias, const __bf16* __restrict__ resB,
    const float* __restrict__ gam, const float* __restrict__ bet,
    float* __restrict__ out)
{
  __shared__ float red[8];
  const int row = blockIdx.x, t = threadIdx.x;
  const size_t ro = (size_t)row * 1024;
  f32x4 v = ((const f32x4*)(P0 + ro))[t];
  f32x4 v1 = ((const f32x4*)(P1 + ro))[t];
  f32x4 bi = ((const f32x4*)bias)[t];
  bf16x4 rb = ((const bf16x4*)(resB + ro))[t];
  float s = 0.f, ss = 0.f;
#pragma unroll
  for (int j = 0; j < 4; ++j) {
    v[j] = v[j] + v1[j] + bi[j] + (float)rb[j];
    s += v[j];
    ss += v[j] * v[j];
  }
#pragma unroll
  for (int o = 1; o < 64; o <<= 1) {
    s += __shfl_xor(s, o, 64);
    ss += __shfl_xor(ss, o, 64);
  }
  int w = t >> 6, l = t & 63;
  if (l == 0) { red[w] = s; red[4 + w] = ss; }
  __syncthreads();
  float S = red[0] + red[1] + red[2] + red[3];
  float SS = red[4] + red[5] + red[6] + red[7];
  float mean = S * (1.f / 1024.f);
  float var = SS * (1.f / 1024.f) - mean * mean;
  float rstd = rsqrtf(var + 1e-5f);
  f32x4 ov;
#pragma unroll
  for (int j = 0; j < 4; ++j) {
    int col = t * 4 + j;
    ov[j] = (v[j] - mean) * rstd * gam[col] + bet[col];
  }
  ((f32x4*)(out + ro))[t] = ov;
}

// ---------------------------------------------------------------------------
extern "C" void kernel_launch(void* const* d_in, const int* in_sizes, int n_in,
                              void* d_out, int out_size, void* d_ws, size_t ws_size,
                              hipStream_t stream) {
  const float* k_in = (const float*)d_in[0];
  const float* v_in = (const float*)d_in[1];
  const float* q_in = (const float*)d_in[2];
  const float* r_in = (const float*)d_in[3];
  const float* Wf = (const float*)d_in[4];
  const float* bf = (const float*)d_in[5];
  const float* g1 = (const float*)d_in[6];
  const float* b1 = (const float*)d_in[7];
  const float* W1 = (const float*)d_in[8];
  const float* bw1 = (const float*)d_in[9];
  const float* W2 = (const float*)d_in[10];
  const float* bw2 = (const float*)d_in[11];
  const float* g2 = (const float*)d_in[12];
  const float* b2 = (const float*)d_in[13];

  float* out0 = (float*)d_out;          // [4096,1024]
  float* attn = out0 + 4194304;         // [64,1024,1024]

  char* W = (char*)d_ws;
  const size_t MB = 1024 * 1024;
  char* KHimg = W + 0;                   // 8MB
  char* KLimg = W + 8 * MB;              // 8MB
  char* VTimg = W + 16 * MB;             // 8MB
  __bf16* WFT = (__bf16*)(W + 24 * MB);  // 2MB
  __bf16* W1T = (__bf16*)(W + 26 * MB);  // 8MB
  __bf16* W2T = (__bf16*)(W + 34 * MB);  // 8MB
  __bf16* CTX = (__bf16*)(W + 42 * MB);  // 8MB
  __bf16* Xb = (__bf16*)(W + 50 * MB);   // 8MB
  __bf16* Hb = (__bf16*)(W + 58 * MB);   // 32MB
  float* T1 = (float*)(W + 90 * MB);     // 16MB
  float* P0 = (float*)(W + 106 * MB);    // 16MB split-K partial 0
  float* P1 = (float*)(W + 122 * MB);    // 16MB split-K partial 1

  prep_all<<<11264, 256, 0, stream>>>(k_in, q_in, KHimg, KLimg, VTimg,
                                      Wf, WFT, W1, W1T, W2, W2T);

  attn_v8<<<512, 512, 0, stream>>>(v_in, KHimg, KLimg, VTimg, attn, CTX);

  // t1 = r + ctx @ Wf + bf
  gemm_bt<0, 64><<<512, 256, 0, stream>>>(CTX, WFT, bf, r_in, nullptr, T1,
                                          nullptr, 4096, 1024, 1024, 1024, 8, 512);
  // x = LN(t1) -> bf16 only
  ln_kernel<0, 1><<<4096, 256, 0, stream>>>(T1, g1, b1, nullptr, Xb);
  // h = relu(x @ W1 + bw1) -> bf16
  gemm_bt<1, 128><<<1024, 256, 0, stream>>>(Xb, W1T, bw1, nullptr, nullptr,
                                            nullptr, Hb, 4096, 4096, 1024, 1024,
                                            32, 1024);
  // split-K=2 partials of h @ W2  (BM=128, 256 tiles x 2 slices)
  gemm_bt<3, 128><<<512, 256, 0, stream>>>(Hb, W2T, nullptr, nullptr, nullptr,
                                           P0, nullptr, 4096, 1024, 4096, 2048,
                                           8, 256);
  // out = LN(P0 + P1 + bw2 + x)
  ln_fuse2<<<4096, 256, 0, stream>>>(P0, P1, bw2, Xb, g2, b2, out0);
}

// Round 10
// 280.816 us; speedup vs baseline: 1.1701x; 1.0612x over previous
//
#include <hip/hip_runtime.h>
#include <hip/hip_bf16.h>
#include <cstdint>

typedef __attribute__((ext_vector_type(8))) __bf16 bf16x8;
typedef __attribute__((ext_vector_type(4))) __bf16 bf16x4;
typedef __attribute__((ext_vector_type(4))) float f32x4;
typedef unsigned int uint32;
typedef unsigned short uint16;

#define LDS_AS __attribute__((address_space(3)))
#define GLB_AS __attribute__((address_space(1)))

static __device__ __forceinline__ void gld_lds16(const void* g, LDS_AS char* l) {
  __builtin_amdgcn_global_load_lds((const GLB_AS uint32*)g, (LDS_AS uint32*)l, 16, 0, 0);
}

#define MFMA(a, b, c) __builtin_amdgcn_mfma_f32_16x16x32_bf16((a), (b), (c), 0, 0, 0)

// 3-term split-bf16 MFMA: A*B ~= Ah*Bh + Al*Bh + Ah*Bl
static __device__ __forceinline__ f32x4 mfma3(bf16x8 ah, bf16x8 al, bf16x8 bh,
                                              bf16x8 bl, f32x4 c) {
  c = MFMA(ah, bh, c);
  c = MFMA(al, bh, c);
  c = MFMA(ah, bl, c);
  return c;
}

static __device__ __forceinline__ uint32 pack_bf16(float a, float b) {
  __bf16 ha = (__bf16)a, hb = (__bf16)b;
  return (uint32)__builtin_bit_cast(uint16, ha) |
         ((uint32)__builtin_bit_cast(uint16, hb) << 16);
}

// XOR swizzle: spreads stride-128B rows across banks (T2, rule #21 both-sides)
#define KB(row, colbyte) ((((row) * 128 + (colbyte))) ^ (((row) & 7) << 4))

// ---------------------------------------------------------------------------
// prep_all: one dispatch for all input preprocessing.
//  blocks 0..1023     : K f32 -> split bf16 hi/lo swizzled images KH/KL
//  blocks 1024..2047  : V f32 -> V^T swizzled image, k-pairs packed u32
//  blocks 2048..3071  : Wf  transpose -> bf16 WFT  [1024x1024]
//  blocks 3072..7167  : W1  transpose -> bf16 W1T  [4096x1024]
//  blocks 7168..11263 : W2  transpose -> bf16 W2T  [1024x4096]
// ---------------------------------------------------------------------------
__global__ __launch_bounds__(256) void prep_all(
    const float* __restrict__ K, const float* __restrict__ V,
    char* __restrict__ KH, char* __restrict__ KL, char* __restrict__ VT,
    const float* __restrict__ Wf, __bf16* __restrict__ WFT,
    const float* __restrict__ W1, __bf16* __restrict__ W1T,
    const float* __restrict__ W2, __bf16* __restrict__ W2T) {
  int b = blockIdx.x;
  if (b < 1024) {
    int kt = b & 15, h = b >> 4;
    const float* src = K + (size_t)h * 65536 + kt * 4096;
    char* dh = KH + (size_t)(h * 16 + kt) * 8192;
    char* dl = KL + (size_t)(h * 16 + kt) * 8192;
    int r = threadIdx.x >> 2, cq = threadIdx.x & 3;
    const float* sp = src + r * 64 + cq * 16;
    bf16x8 h0, l0, h1, l1;
#pragma unroll
    for (int j = 0; j < 8; ++j) {
      float x0 = sp[j], x1 = sp[8 + j];
      __bf16 a = (__bf16)x0, bb = (__bf16)x1;
      h0[j] = a; l0[j] = (__bf16)(x0 - (float)a);
      h1[j] = bb; l1[j] = (__bf16)(x1 - (float)bb);
    }
    int sw = (r & 7) << 4;
    int o0 = (r * 128 + cq * 32) ^ sw;
    int o1 = (r * 128 + cq * 32 + 16) ^ sw;
    *(bf16x8*)(dh + o0) = h0;
    *(bf16x8*)(dh + o1) = h1;
    *(bf16x8*)(dl + o0) = l0;
    *(bf16x8*)(dl + o1) = l1;
    return;
  }
  if (b < 2048) {
    b -= 1024;
    int kt = b & 15, h = b >> 4;
    const float* src = V + (size_t)h * 65536 + kt * 4096;
    char* dv = VT + (size_t)(h * 16 + kt) * 8192;
    int kp = threadIdx.x >> 3, dq = threadIdx.x & 7;
    const float* s0 = src + (2 * kp) * 64 + dq * 8;
    const float* s1 = s0 + 64;
#pragma unroll
    for (int j = 0; j < 8; ++j) {
      uint32 pk = pack_bf16(s0[j], s1[j]);
      int d = dq * 8 + j;
      *(uint32*)(dv + ((d * 128 + kp * 4) ^ ((d & 7) << 4))) = pk;
    }
    return;
  }
  // transposes
  const float* in;
  __bf16* out;
  int R, C, bx, by;
  if (b < 3072) {
    b -= 2048; in = Wf; out = WFT; R = 1024; C = 1024;
    bx = (b & 31) * 32; by = (b >> 5) * 32;
  } else if (b < 7168) {
    b -= 3072; in = W1; out = W1T; R = 1024; C = 4096;
    bx = (b & 127) * 32; by = (b >> 7) * 32;
  } else {
    b -= 7168; in = W2; out = W2T; R = 4096; C = 1024;
    bx = (b & 31) * 32; by = (b >> 5) * 32;
  }
  __shared__ float tile[32][33];
  int tx = threadIdx.x & 31, ty = threadIdx.x >> 5;
  for (int i = ty; i < 32; i += 8)
    tile[i][tx] = in[(size_t)(by + i) * C + bx + tx];
  __syncthreads();
  for (int i = ty; i < 32; i += 8)
    out[(size_t)(bx + i) * R + by + tx] = (__bf16)tile[tx][i];
}

// ---------------------------------------------------------------------------
// Attention v8 (unchanged from round 9 — it just won; don't touch).
// Block = (head g, 128-row q block rb), 8 waves x 16 q rows.
// Q = v_input, K = k_input, V = q_input (reference signature quirk).
// ---------------------------------------------------------------------------
__global__ __launch_bounds__(512, 4) void attn_v8(
    const float* __restrict__ Qin, const char* __restrict__ KHimg,
    const char* __restrict__ KLimg, const char* __restrict__ VTimg,
    float* __restrict__ attn_out, __bf16* __restrict__ ctx_out)
{
  __shared__ __attribute__((aligned(16))) char KsH[2][8192];
  __shared__ __attribute__((aligned(16))) char KsL[2][8192];
  __shared__ __attribute__((aligned(16))) char Vt[2][8192];
  __shared__ __attribute__((aligned(16))) __bf16 PsH[8][16][72];

  const int tid = threadIdx.x;
  const int l = tid & 63, w = tid >> 6;
  const int lr = l & 15, q4 = l >> 4;
  const int swz = (blockIdx.x & 7) * 64 + (blockIdx.x >> 3);  // XCD chunking
  const int g = swz >> 3, rb = swz & 7;
  const size_t base = (size_t)g * 65536;
  const char* khb = KHimg + (size_t)g * 131072;
  const char* klb = KLimg + (size_t)g * 131072;
  const char* vtb = VTimg + (size_t)g * 131072;

  const float* qp = Qin + base + (size_t)(rb * 128 + w * 16 + lr) * 64;
  f32x4 qv[4];
#pragma unroll
  for (int j = 0; j < 2; ++j) {
    qv[j] = *(const f32x4*)&qp[q4 * 8 + j * 4];
    qv[2 + j] = *(const f32x4*)&qp[32 + q4 * 8 + j * 4];
  }

  gld_lds16(khb + 0 * 8192 + tid * 16, (LDS_AS char*)&KsH[0][0] + tid * 16);
  gld_lds16(klb + 0 * 8192 + tid * 16, (LDS_AS char*)&KsL[0][0] + tid * 16);

  bf16x8 aqh0, aql0, aqh1, aql1;
#pragma unroll
  for (int j = 0; j < 8; ++j) {
    float x0 = qv[j >> 2][j & 3];
    float x1 = qv[2 + (j >> 2)][j & 3];
    __bf16 h0 = (__bf16)x0, h1 = (__bf16)x1;
    aqh0[j] = h0; aql0[j] = (__bf16)(x0 - (float)h0);
    aqh1[j] = h1; aql1[j] = (__bf16)(x1 - (float)h1);
  }

  float m_r[4], ll_r[4];
#pragma unroll
  for (int r = 0; r < 4; ++r) { m_r[r] = -1e30f; ll_r[r] = 0.f; }

  // ---- pass 1: stats (lane-local online softmax, zero shfl in loop) ----
  for (int kt = 0; kt < 16; ++kt) {
    const int buf = kt & 1;
    if (kt < 15) {
      gld_lds16(khb + (kt + 1) * 8192 + tid * 16,
                (LDS_AS char*)&KsH[buf ^ 1][0] + tid * 16);
      gld_lds16(klb + (kt + 1) * 8192 + tid * 16,
                (LDS_AS char*)&KsL[buf ^ 1][0] + tid * 16);
      asm volatile("s_waitcnt vmcnt(2)" ::: "memory");
    } else {
      asm volatile("s_waitcnt vmcnt(0)" ::: "memory");
    }
    __builtin_amdgcn_s_barrier();
    const char* ksh = KsH[buf];
    const char* ksl = KsL[buf];
    f32x4 c[4];
#pragma unroll
    for (int nf = 0; nf < 4; ++nf) {
      int row = nf * 16 + lr;
      f32x4 cc = {0.f, 0.f, 0.f, 0.f};
      cc = mfma3(aqh0, aql0, *(const bf16x8*)(ksh + KB(row, q4 * 16)),
                 *(const bf16x8*)(ksl + KB(row, q4 * 16)), cc);
      cc = mfma3(aqh1, aql1, *(const bf16x8*)(ksh + KB(row, 64 + q4 * 16)),
                 *(const bf16x8*)(ksl + KB(row, 64 + q4 * 16)), cc);
      c[nf] = cc;
    }
#pragma unroll
    for (int r = 0; r < 4; ++r) {
      float s0 = c[0][r] * 8.f, s1 = c[1][r] * 8.f;
      float s2 = c[2][r] * 8.f, s3 = c[3][r] * 8.f;
      float lm = fmaxf(fmaxf(s0, s1), fmaxf(s2, s3));
      float mnew = fmaxf(m_r[r], lm);
      ll_r[r] = ll_r[r] * __expf(m_r[r] - mnew) +
                (__expf(s0 - mnew) + __expf(s1 - mnew) +
                 __expf(s2 - mnew) + __expf(s3 - mnew));
      m_r[r] = mnew;
    }
    __builtin_amdgcn_s_barrier();
  }
  float inv_l[4];
#pragma unroll
  for (int r = 0; r < 4; ++r) {
    float M = m_r[r];
#pragma unroll
    for (int o = 1; o < 16; o <<= 1) M = fmaxf(M, __shfl_xor(M, o, 64));
    float ls = ll_r[r] * __expf(m_r[r] - M);
#pragma unroll
    for (int o = 1; o < 16; o <<= 1) ls += __shfl_xor(ls, o, 64);
    m_r[r] = M;
    inv_l[r] = 1.f / ls;
  }

  f32x4 co[4];
#pragma unroll
  for (int cf = 0; cf < 4; ++cf) co[cf] = (f32x4){0.f, 0.f, 0.f, 0.f};

  gld_lds16(khb + 0 * 8192 + tid * 16, (LDS_AS char*)&KsH[0][0] + tid * 16);
  gld_lds16(klb + 0 * 8192 + tid * 16, (LDS_AS char*)&KsL[0][0] + tid * 16);
  gld_lds16(vtb + 0 * 8192 + tid * 16, (LDS_AS char*)&Vt[0][0] + tid * 16);

  // ---- pass 2: P (nt f32 attn out + bf16 Ps) + PV ----
  for (int kt = 0; kt < 16; ++kt) {
    const int buf = kt & 1;
    if (kt < 15) {
      gld_lds16(khb + (kt + 1) * 8192 + tid * 16,
                (LDS_AS char*)&KsH[buf ^ 1][0] + tid * 16);
      gld_lds16(klb + (kt + 1) * 8192 + tid * 16,
                (LDS_AS char*)&KsL[buf ^ 1][0] + tid * 16);
      gld_lds16(vtb + (kt + 1) * 8192 + tid * 16,
                (LDS_AS char*)&Vt[buf ^ 1][0] + tid * 16);
    }
    if (kt == 0) {
      asm volatile("s_waitcnt vmcnt(3)" ::: "memory");
    } else if (kt < 15) {
      asm volatile("s_waitcnt vmcnt(19)" ::: "memory");
    } else {
      asm volatile("s_waitcnt vmcnt(16)" ::: "memory");
    }
    __builtin_amdgcn_s_barrier();
    const char* ksh = KsH[buf];
    const char* ksl = KsL[buf];
    const char* vts = Vt[buf];
#pragma unroll
    for (int nf = 0; nf < 4; ++nf) {
      int row = nf * 16 + lr;
      f32x4 cc = {0.f, 0.f, 0.f, 0.f};
      cc = mfma3(aqh0, aql0, *(const bf16x8*)(ksh + KB(row, q4 * 16)),
                 *(const bf16x8*)(ksl + KB(row, q4 * 16)), cc);
      cc = mfma3(aqh1, aql1, *(const bf16x8*)(ksh + KB(row, 64 + q4 * 16)),
                 *(const bf16x8*)(ksl + KB(row, 64 + q4 * 16)), cc);
#pragma unroll
      for (int r = 0; r < 4; ++r) {
        float p = __expf(cc[r] * 8.f - m_r[r]) * inv_l[r];
        PsH[w][q4 * 4 + r][nf * 16 + lr] = (__bf16)p;
        int arow = rb * 128 + w * 16 + q4 * 4 + r;
        __builtin_nontemporal_store(
            p, &attn_out[((size_t)(g * 1024 + arow)) * 1024 + kt * 64 + nf * 16 + lr]);
      }
    }
#pragma unroll
    for (int kk = 0; kk < 2; ++kk) {
      bf16x8 ph = *(const bf16x8*)&PsH[w][lr][kk * 32 + q4 * 8];
#pragma unroll
      for (int cf = 0; cf < 4; ++cf) {
        bf16x8 vt = *(const bf16x8*)(vts + KB(cf * 16 + lr, kk * 64 + q4 * 16));
        co[cf] = MFMA(ph, vt, co[cf]);
      }
    }
    __builtin_amdgcn_s_barrier();
  }
#pragma unroll
  for (int cf = 0; cf < 4; ++cf)
#pragma unroll
    for (int r = 0; r < 4; ++r) {
      int i = rb * 128 + w * 16 + q4 * 4 + r;
      ctx_out[((size_t)(g * 1024 + i)) * 64 + cf * 16 + lr] = (__bf16)co[cf][r];
    }
}

// ---------------------------------------------------------------------------
// gemm_db: 2-phase double-buffered GEMM (T3-min pipeline, attn_v5-proven).
// C = A[MxK] * Bt[NxK]^T. Tile BM x 128, 4 waves, XCD-chunked 1D grid.
// EPI 3: Outf = acc (split-K partial). EPI 4: Outb = bf16(acc+bias+Res f32).
// LDS: 2 x (BM*64 A + 128*64 B) bf16 = 48KB (BM=64) / 64KB (BM=128).
// ---------------------------------------------------------------------------
template <int EPI, int BM>
__global__ __launch_bounds__(256) void gemm_db(
    const __bf16* __restrict__ A, const __bf16* __restrict__ Bt,
    const float* __restrict__ bias, const float* __restrict__ Res,
    float* __restrict__ Outf, __bf16* __restrict__ Outb,
    int M, int N, int K, int Kloop, int nbx, int tiles_per_out)
{
  constexpr int MF = BM / 32;
  constexpr int ELEMS = BM * 64 + 8192;
  __shared__ __attribute__((aligned(16))) __bf16 sm[2][ELEMS];
  const int tid = threadIdx.x;
  const int l = tid & 63, w = tid >> 6;
  const int lr = l & 15, lkb = (l >> 4) * 8;
  const int nwg = gridDim.x;
  const int swz = (blockIdx.x & 7) * (nwg >> 3) + (blockIdx.x >> 3);
  const int ks = swz / tiles_per_out;
  const int tile = swz % tiles_per_out;
  const int m0 = (tile / nbx) * BM, n0 = (tile % nbx) * 128;
  const int kbase = ks * Kloop;
  const int wr = (w >> 1) * (BM / 2), wc = (w & 1) * 64;

  f32x4 acc[MF][4];
  f32x4 zero = {0.f, 0.f, 0.f, 0.f};
#pragma unroll
  for (int m = 0; m < MF; ++m)
#pragma unroll
    for (int n = 0; n < 4; ++n) acc[m][n] = zero;

  const int nkt = Kloop >> 6;

#define GSTAGE(BUF, KT)                                                        \
  {                                                                            \
    LDS_AS char* dst = (LDS_AS char*)&sm[(BUF)][0];                            \
    _Pragma("unroll") for (int it = 0; it < MF; ++it) {                        \
      int slot = it * 256 + tid;                                               \
      int row = slot >> 3, cb = slot & 7;                                      \
      gld_lds16(&A[(size_t)(m0 + row) * K + kbase + (KT) * 64 + cb * 8],       \
                dst + slot * 16);                                              \
    }                                                                          \
    _Pragma("unroll") for (int it = 0; it < 4; ++it) {                         \
      int slot = it * 256 + tid;                                               \
      int row = slot >> 3, cb = slot & 7;                                      \
      gld_lds16(&Bt[(size_t)(n0 + row) * K + kbase + (KT) * 64 + cb * 8],      \
                dst + BM * 128 + slot * 16);                                   \
    }                                                                          \
  }

  GSTAGE(0, 0);
  for (int kt = 0; kt < nkt; ++kt) {
    const int buf = kt & 1;
    if (kt < nkt - 1) {
      GSTAGE(buf ^ 1, kt + 1);
      if (BM == 64) {
        asm volatile("s_waitcnt vmcnt(6)" ::: "memory");
      } else {
        asm volatile("s_waitcnt vmcnt(8)" ::: "memory");
      }
    } else {
      asm volatile("s_waitcnt vmcnt(0)" ::: "memory");
    }
    __builtin_amdgcn_s_barrier();
    const __bf16* s = &sm[buf][0];
#pragma unroll
    for (int kk = 0; kk < 2; ++kk) {
      bf16x8 a[MF], b[4];
#pragma unroll
      for (int m = 0; m < MF; ++m)
        a[m] = *(const bf16x8*)&s[(wr + m * 16 + lr) * 64 + kk * 32 + lkb];
#pragma unroll
      for (int n = 0; n < 4; ++n)
        b[n] = *(const bf16x8*)&s[BM * 64 + (wc + n * 16 + lr) * 64 + kk * 32 + lkb];
#pragma unroll
      for (int m = 0; m < MF; ++m)
#pragma unroll
        for (int n = 0; n < 4; ++n) acc[m][n] = MFMA(a[m], b[n], acc[m][n]);
    }
    __builtin_amdgcn_s_barrier();
  }
#undef GSTAGE

  float* outp = (EPI == 3) ? Outf + (size_t)ks * M * N : Outf;
#pragma unroll
  for (int n = 0; n < 4; ++n) {
    int gcol = n0 + wc + n * 16 + lr;
    float bc = (EPI == 3) ? 0.f : bias[gcol];
#pragma unroll
    for (int m = 0; m < MF; ++m) {
      int grow = m0 + wr + m * 16 + (l >> 4) * 4;
#pragma unroll
      for (int r = 0; r < 4; ++r) {
        float v = acc[m][n][r] + bc;
        size_t o = (size_t)(grow + r) * N + gcol;
        if (EPI == 4) {
          Outb[o] = (__bf16)(v + Res[o]);
        } else {
          outp[o] = v;
        }
      }
    }
  }
}

// ---------------------------------------------------------------------------
// m97-structure sync GEMM (kept for gemm2: 4 blocks/CU, TLP hides drain).
// EPI 1: Outb = bf16(relu(acc+bias)).
// ---------------------------------------------------------------------------
template <int EPI, int BM>
__global__ __launch_bounds__(256) void gemm_bt(
    const __bf16* __restrict__ A, const __bf16* __restrict__ Bt,
    const float* __restrict__ bias, __bf16* __restrict__ Outb,
    int M, int N, int K, int nbx)
{
  constexpr int MF = BM / 32;
  __shared__ __attribute__((aligned(16))) __bf16 sm[BM * 64 + 8192];
  const int tid = threadIdx.x;
  const int l = tid & 63, w = tid >> 6;
  const int lr = l & 15, lkb = (l >> 4) * 8;
  const int nwg = gridDim.x;
  const int swz = (blockIdx.x & 7) * (nwg >> 3) + (blockIdx.x >> 3);
  const int m0 = (swz / nbx) * BM, n0 = (swz % nbx) * 128;
  const int wr = (w >> 1) * (BM / 2), wc = (w & 1) * 64;
  LDS_AS char* sm3 = (LDS_AS char*)sm;

  f32x4 acc[MF][4];
  f32x4 zero = {0.f, 0.f, 0.f, 0.f};
#pragma unroll
  for (int m = 0; m < MF; ++m)
#pragma unroll
    for (int n = 0; n < 4; ++n) acc[m][n] = zero;

  const int nkt = K >> 6;
  for (int kt = 0; kt < nkt; ++kt) {
    __syncthreads();
#pragma unroll
    for (int it = 0; it < MF; ++it) {
      int slot = it * 256 + tid;
      int row = slot >> 3, cb = slot & 7;
      gld_lds16(&A[(size_t)(m0 + row) * K + kt * 64 + cb * 8], sm3 + slot * 16);
    }
#pragma unroll
    for (int it = 0; it < 4; ++it) {
      int slot = it * 256 + tid;
      int row = slot >> 3, cb = slot & 7;
      gld_lds16(&Bt[(size_t)(n0 + row) * K + kt * 64 + cb * 8],
                sm3 + BM * 128 + slot * 16);
    }
    __syncthreads();
#pragma unroll
    for (int kk = 0; kk < 2; ++kk) {
      bf16x8 a[MF], b[4];
#pragma unroll
      for (int m = 0; m < MF; ++m)
        a[m] = *(const bf16x8*)&sm[(wr + m * 16 + lr) * 64 + kk * 32 + lkb];
#pragma unroll
      for (int n = 0; n < 4; ++n)
        b[n] = *(const bf16x8*)&sm[BM * 64 + (wc + n * 16 + lr) * 64 + kk * 32 + lkb];
#pragma unroll
      for (int m = 0; m < MF; ++m)
#pragma unroll
        for (int n = 0; n < 4; ++n) acc[m][n] = MFMA(a[m], b[n], acc[m][n]);
    }
  }

#pragma unroll
  for (int n = 0; n < 4; ++n) {
    int gcol = n0 + wc + n * 16 + lr;
    float bc = bias[gcol];
#pragma unroll
    for (int m = 0; m < MF; ++m) {
      int grow = m0 + wr + m * 16 + (l >> 4) * 4;
#pragma unroll
      for (int r = 0; r < 4; ++r) {
        float v = acc[m][n][r] + bc;
        size_t o = (size_t)(grow + r) * N + gcol;
        Outb[o] = (__bf16)fmaxf(v, 0.f);
      }
    }
  }
}

// ---------------------------------------------------------------------------
// LayerNorm over D=1024, bf16 in -> bf16 out, one block per row.
// ---------------------------------------------------------------------------
__global__ __launch_bounds__(256) void ln_b2b(
    const __bf16* __restrict__ in, const float* __restrict__ gam,
    const float* __restrict__ bet, __bf16* __restrict__ outB)
{
  __shared__ float red[8];
  const int row = blockIdx.x, t = threadIdx.x;
  bf16x4 vb = ((const bf16x4*)(in + (size_t)row * 1024))[t];
  float v[4];
  float s = 0.f, ss = 0.f;
#pragma unroll
  for (int j = 0; j < 4; ++j) {
    v[j] = (float)vb[j];
    s += v[j];
    ss += v[j] * v[j];
  }
#pragma unroll
  for (int o = 1; o < 64; o <<= 1) {
    s += __shfl_xor(s, o, 64);
    ss += __shfl_xor(ss, o, 64);
  }
  int w = t >> 6, l = t & 63;
  if (l == 0) { red[w] = s; red[4 + w] = ss; }
  __syncthreads();
  float S = red[0] + red[1] + red[2] + red[3];
  float SS = red[4] + red[5] + red[6] + red[7];
  float mean = S * (1.f / 1024.f);
  float var = SS * (1.f / 1024.f) - mean * mean;
  float rstd = rsqrtf(var + 1e-5f);
  bf16x4 ob;
#pragma unroll
  for (int j = 0; j < 4; ++j) {
    int col = t * 4 + j;
    ob[j] = (__bf16)((v[j] - mean) * rstd * gam[col] + bet[col]);
  }
  ((bf16x4*)(outB + (size_t)row * 1024))[t] = ob;
}

// ---------------------------------------------------------------------------
// Fused final LN: x = P0 + P1 + bias + resB (bf16), out = LN(x)*g + b (f32)
// ---------------------------------------------------------------------------
__global__ __launch_bounds__(256) void ln_fuse2(
    const float* __restrict__ P0, const float* __restrict__ P1,
    const float* __restrict__ bias, const __bf16* __restrict__ resB,
    const float* __restrict__ gam, const float* __restrict__ bet,
    float* __restrict__ out)
{
  __shared__ float red[8];
  const int row = blockIdx.x, t = threadIdx.x;
  const size_t ro = (size_t)row * 1024;
  f32x4 v = ((const f32x4*)(P0 + ro))[t];
  f32x4 v1 = ((const f32x4*)(P1 + ro))[t];
  f32x4 bi = ((const f32x4*)bias)[t];
  bf16x4 rb = ((const bf16x4*)(resB + ro))[t];
  float s = 0.f, ss = 0.f;
#pragma unroll
  for (int j = 0; j < 4; ++j) {
    v[j] = v[j] + v1[j] + bi[j] + (float)rb[j];
    s += v[j];
    ss += v[j] * v[j];
  }
#pragma unroll
  for (int o = 1; o < 64; o <<= 1) {
    s += __shfl_xor(s, o, 64);
    ss += __shfl_xor(ss, o, 64);
  }
  int w = t >> 6, l = t & 63;
  if (l == 0) { red[w] = s; red[4 + w] = ss; }
  __syncthreads();
  float S = red[0] + red[1] + red[2] + red[3];
  float SS = red[4] + red[5] + red[6] + red[7];
  float mean = S * (1.f / 1024.f);
  float var = SS * (1.f / 1024.f) - mean * mean;
  float rstd = rsqrtf(var + 1e-5f);
  f32x4 ov;
#pragma unroll
  for (int j = 0; j < 4; ++j) {
    int col = t * 4 + j;
    ov[j] = (v[j] - mean) * rstd * gam[col] + bet[col];
  }
  ((f32x4*)(out + ro))[t] = ov;
}

// ---------------------------------------------------------------------------
extern "C" void kernel_launch(void* const* d_in, const int* in_sizes, int n_in,
                              void* d_out, int out_size, void* d_ws, size_t ws_size,
                              hipStream_t stream) {
  const float* k_in = (const float*)d_in[0];
  const float* v_in = (const float*)d_in[1];
  const float* q_in = (const float*)d_in[2];
  const float* r_in = (const float*)d_in[3];
  const float* Wf = (const float*)d_in[4];
  const float* bf = (const float*)d_in[5];
  const float* g1 = (const float*)d_in[6];
  const float* b1 = (const float*)d_in[7];
  const float* W1 = (const float*)d_in[8];
  const float* bw1 = (const float*)d_in[9];
  const float* W2 = (const float*)d_in[10];
  const float* bw2 = (const float*)d_in[11];
  const float* g2 = (const float*)d_in[12];
  const float* b2 = (const float*)d_in[13];

  float* out0 = (float*)d_out;          // [4096,1024]
  float* attn = out0 + 4194304;         // [64,1024,1024]

  char* W = (char*)d_ws;
  const size_t MB = 1024 * 1024;
  char* KHimg = W + 0;                   // 8MB
  char* KLimg = W + 8 * MB;              // 8MB
  char* VTimg = W + 16 * MB;             // 8MB
  __bf16* WFT = (__bf16*)(W + 24 * MB);  // 2MB
  __bf16* W1T = (__bf16*)(W + 26 * MB);  // 8MB
  __bf16* W2T = (__bf16*)(W + 34 * MB);  // 8MB
  __bf16* CTX = (__bf16*)(W + 42 * MB);  // 8MB
  __bf16* Xb = (__bf16*)(W + 50 * MB);   // 8MB
  __bf16* Hb = (__bf16*)(W + 58 * MB);   // 32MB
  __bf16* T1b = (__bf16*)(W + 90 * MB);  // 8MB
  float* P0 = (float*)(W + 106 * MB);    // 16MB split-K partial 0
  float* P1 = (float*)(W + 122 * MB);    // 16MB split-K partial 1

  prep_all<<<11264, 256, 0, stream>>>(k_in, q_in, KHimg, KLimg, VTimg,
                                      Wf, WFT, W1, W1T, W2, W2T);

  attn_v8<<<512, 512, 0, stream>>>(v_in, KHimg, KLimg, VTimg, attn, CTX);

  // t1 = bf16(r + ctx @ Wf + bf)   [dbuf pipeline]
  gemm_db<4, 64><<<512, 256, 0, stream>>>(CTX, WFT, bf, r_in, nullptr, T1b,
                                          4096, 1024, 1024, 1024, 8, 512);
  // x = LN(t1) -> bf16
  ln_b2b<<<4096, 256, 0, stream>>>(T1b, g1, b1, Xb);
  // h = relu(x @ W1 + bw1) -> bf16  [sync structure, 4 blocks/CU]
  gemm_bt<1, 128><<<1024, 256, 0, stream>>>(Xb, W1T, bw1, Hb, 4096, 4096, 1024, 32);
  // split-K=2 partials of h @ W2   [dbuf pipeline]
  gemm_db<3, 128><<<512, 256, 0, stream>>>(Hb, W2T, nullptr, nullptr, P0, nullptr,
                                           4096, 1024, 4096, 2048, 8, 256);
  // out = LN(P0 + P1 + bw2 + x)
  ln_fuse2<<<4096, 256, 0, stream>>>(P0, P1, bw2, Xb, g2, b2, out0);
}

// Round 12
// 268.869 us; speedup vs baseline: 1.2221x; 1.0444x over previous
//
#include <hip/hip_runtime.h>
#include <hip/hip_bf16.h>
#include <cstdint>

typedef __attribute__((ext_vector_type(8))) __bf16 bf16x8;
typedef __attribute__((ext_vector_type(4))) __bf16 bf16x4;
typedef __attribute__((ext_vector_type(4))) float f32x4;
typedef unsigned int uint32;
typedef unsigned short uint16;

#define LDS_AS __attribute__((address_space(3)))
#define GLB_AS __attribute__((address_space(1)))

static __device__ __forceinline__ void gld_lds16(const void* g, LDS_AS char* l) {
  __builtin_amdgcn_global_load_lds((const GLB_AS uint32*)g, (LDS_AS uint32*)l, 16, 0, 0);
}

#define MFMA(a, b, c) __builtin_amdgcn_mfma_f32_16x16x32_bf16((a), (b), (c), 0, 0, 0)

// 3-term split-bf16 MFMA: A*B ~= Ah*Bh + Al*Bh + Ah*Bl
static __device__ __forceinline__ f32x4 mfma3(bf16x8 ah, bf16x8 al, bf16x8 bh,
                                              bf16x8 bl, f32x4 c) {
  c = MFMA(ah, bh, c);
  c = MFMA(al, bh, c);
  c = MFMA(ah, bl, c);
  return c;
}

static __device__ __forceinline__ uint32 pack_bf16(float a, float b) {
  __bf16 ha = (__bf16)a, hb = (__bf16)b;
  return (uint32)__builtin_bit_cast(uint16, ha) |
         ((uint32)__builtin_bit_cast(uint16, hb) << 16);
}

// XOR swizzle: spreads stride-128B rows across banks (T2, rule #21 both-sides)
#define KB(row, colbyte) ((((row) * 128 + (colbyte))) ^ (((row) & 7) << 4))

// ---------------------------------------------------------------------------
// prep_all: one dispatch for all input preprocessing.
//  blocks 0..1023     : K f32 -> split bf16 hi/lo swizzled images KH/KL
//  blocks 1024..2047  : V f32 -> V^T swizzled image, k-pairs packed u32
//  blocks 2048..3071  : Wf  transpose -> bf16 WFT  [1024x1024]
//  blocks 3072..7167  : W1  transpose -> bf16 W1T  [4096x1024]
//  blocks 7168..11263 : W2  transpose -> bf16 W2T  [1024x4096]
// ---------------------------------------------------------------------------
__global__ __launch_bounds__(256) void prep_all(
    const float* __restrict__ K, const float* __restrict__ V,
    char* __restrict__ KH, char* __restrict__ KL, char* __restrict__ VT,
    const float* __restrict__ Wf, __bf16* __restrict__ WFT,
    const float* __restrict__ W1, __bf16* __restrict__ W1T,
    const float* __restrict__ W2, __bf16* __restrict__ W2T) {
  int b = blockIdx.x;
  if (b < 1024) {
    int kt = b & 15, h = b >> 4;
    const float* src = K + (size_t)h * 65536 + kt * 4096;
    char* dh = KH + (size_t)(h * 16 + kt) * 8192;
    char* dl = KL + (size_t)(h * 16 + kt) * 8192;
    int r = threadIdx.x >> 2, cq = threadIdx.x & 3;
    const float* sp = src + r * 64 + cq * 16;
    bf16x8 h0, l0, h1, l1;
#pragma unroll
    for (int j = 0; j < 8; ++j) {
      float x0 = sp[j], x1 = sp[8 + j];
      __bf16 a = (__bf16)x0, bb = (__bf16)x1;
      h0[j] = a; l0[j] = (__bf16)(x0 - (float)a);
      h1[j] = bb; l1[j] = (__bf16)(x1 - (float)bb);
    }
    int sw = (r & 7) << 4;
    int o0 = (r * 128 + cq * 32) ^ sw;
    int o1 = (r * 128 + cq * 32 + 16) ^ sw;
    *(bf16x8*)(dh + o0) = h0;
    *(bf16x8*)(dh + o1) = h1;
    *(bf16x8*)(dl + o0) = l0;
    *(bf16x8*)(dl + o1) = l1;
    return;
  }
  if (b < 2048) {
    b -= 1024;
    int kt = b & 15, h = b >> 4;
    const float* src = V + (size_t)h * 65536 + kt * 4096;
    char* dv = VT + (size_t)(h * 16 + kt) * 8192;
    int kp = threadIdx.x >> 3, dq = threadIdx.x & 7;
    const float* s0 = src + (2 * kp) * 64 + dq * 8;
    const float* s1 = s0 + 64;
#pragma unroll
    for (int j = 0; j < 8; ++j) {
      uint32 pk = pack_bf16(s0[j], s1[j]);
      int d = dq * 8 + j;
      *(uint32*)(dv + ((d * 128 + kp * 4) ^ ((d & 7) << 4))) = pk;
    }
    return;
  }
  // transposes
  const float* in;
  __bf16* out;
  int R, C, bx, by;
  if (b < 3072) {
    b -= 2048; in = Wf; out = WFT; R = 1024; C = 1024;
    bx = (b & 31) * 32; by = (b >> 5) * 32;
  } else if (b < 7168) {
    b -= 3072; in = W1; out = W1T; R = 1024; C = 4096;
    bx = (b & 127) * 32; by = (b >> 7) * 32;
  } else {
    b -= 7168; in = W2; out = W2T; R = 4096; C = 1024;
    bx = (b & 31) * 32; by = (b >> 5) * 32;
  }
  __shared__ float tile[32][33];
  int tx = threadIdx.x & 31, ty = threadIdx.x >> 5;
  for (int i = ty; i < 32; i += 8)
    tile[i][tx] = in[(size_t)(by + i) * C + bx + tx];
  __syncthreads();
  for (int i = ty; i < 32; i += 8)
    out[(size_t)(bx + i) * R + by + tx] = (__bf16)tile[tx][i];
}

// ---------------------------------------------------------------------------
// Attention v8 (unchanged — round-9 winner).
// Block = (head g, 128-row q block rb), 8 waves x 16 q rows.
// Q = v_input, K = k_input, V = q_input (reference signature quirk).
// ---------------------------------------------------------------------------
__global__ __launch_bounds__(512, 4) void attn_v8(
    const float* __restrict__ Qin, const char* __restrict__ KHimg,
    const char* __restrict__ KLimg, const char* __restrict__ VTimg,
    float* __restrict__ attn_out, __bf16* __restrict__ ctx_out)
{
  __shared__ __attribute__((aligned(16))) char KsH[2][8192];
  __shared__ __attribute__((aligned(16))) char KsL[2][8192];
  __shared__ __attribute__((aligned(16))) char Vt[2][8192];
  __shared__ __attribute__((aligned(16))) __bf16 PsH[8][16][72];

  const int tid = threadIdx.x;
  const int l = tid & 63, w = tid >> 6;
  const int lr = l & 15, q4 = l >> 4;
  const int swz = (blockIdx.x & 7) * 64 + (blockIdx.x >> 3);  // XCD chunking
  const int g = swz >> 3, rb = swz & 7;
  const size_t base = (size_t)g * 65536;
  const char* khb = KHimg + (size_t)g * 131072;
  const char* klb = KLimg + (size_t)g * 131072;
  const char* vtb = VTimg + (size_t)g * 131072;

  const float* qp = Qin + base + (size_t)(rb * 128 + w * 16 + lr) * 64;
  f32x4 qv[4];
#pragma unroll
  for (int j = 0; j < 2; ++j) {
    qv[j] = *(const f32x4*)&qp[q4 * 8 + j * 4];
    qv[2 + j] = *(const f32x4*)&qp[32 + q4 * 8 + j * 4];
  }

  gld_lds16(khb + 0 * 8192 + tid * 16, (LDS_AS char*)&KsH[0][0] + tid * 16);
  gld_lds16(klb + 0 * 8192 + tid * 16, (LDS_AS char*)&KsL[0][0] + tid * 16);

  bf16x8 aqh0, aql0, aqh1, aql1;
#pragma unroll
  for (int j = 0; j < 8; ++j) {
    float x0 = qv[j >> 2][j & 3];
    float x1 = qv[2 + (j >> 2)][j & 3];
    __bf16 h0 = (__bf16)x0, h1 = (__bf16)x1;
    aqh0[j] = h0; aql0[j] = (__bf16)(x0 - (float)h0);
    aqh1[j] = h1; aql1[j] = (__bf16)(x1 - (float)h1);
  }

  float m_r[4], ll_r[4];
#pragma unroll
  for (int r = 0; r < 4; ++r) { m_r[r] = -1e30f; ll_r[r] = 0.f; }

  // ---- pass 1: stats (lane-local online softmax, zero shfl in loop) ----
  for (int kt = 0; kt < 16; ++kt) {
    const int buf = kt & 1;
    if (kt < 15) {
      gld_lds16(khb + (kt + 1) * 8192 + tid * 16,
                (LDS_AS char*)&KsH[buf ^ 1][0] + tid * 16);
      gld_lds16(klb + (kt + 1) * 8192 + tid * 16,
                (LDS_AS char*)&KsL[buf ^ 1][0] + tid * 16);
      asm volatile("s_waitcnt vmcnt(2)" ::: "memory");
    } else {
      asm volatile("s_waitcnt vmcnt(0)" ::: "memory");
    }
    __builtin_amdgcn_s_barrier();
    const char* ksh = KsH[buf];
    const char* ksl = KsL[buf];
    f32x4 c[4];
#pragma unroll
    for (int nf = 0; nf < 4; ++nf) {
      int row = nf * 16 + lr;
      f32x4 cc = {0.f, 0.f, 0.f, 0.f};
      cc = mfma3(aqh0, aql0, *(const bf16x8*)(ksh + KB(row, q4 * 16)),
                 *(const bf16x8*)(ksl + KB(row, q4 * 16)), cc);
      cc = mfma3(aqh1, aql1, *(const bf16x8*)(ksh + KB(row, 64 + q4 * 16)),
                 *(const bf16x8*)(ksl + KB(row, 64 + q4 * 16)), cc);
      c[nf] = cc;
    }
#pragma unroll
    for (int r = 0; r < 4; ++r) {
      float s0 = c[0][r] * 8.f, s1 = c[1][r] * 8.f;
      float s2 = c[2][r] * 8.f, s3 = c[3][r] * 8.f;
      float lm = fmaxf(fmaxf(s0, s1), fmaxf(s2, s3));
      float mnew = fmaxf(m_r[r], lm);
      ll_r[r] = ll_r[r] * __expf(m_r[r] - mnew) +
                (__expf(s0 - mnew) + __expf(s1 - mnew) +
                 __expf(s2 - mnew) + __expf(s3 - mnew));
      m_r[r] = mnew;
    }
    __builtin_amdgcn_s_barrier();
  }
  float inv_l[4];
#pragma unroll
  for (int r = 0; r < 4; ++r) {
    float M = m_r[r];
#pragma unroll
    for (int o = 1; o < 16; o <<= 1) M = fmaxf(M, __shfl_xor(M, o, 64));
    float ls = ll_r[r] * __expf(m_r[r] - M);
#pragma unroll
    for (int o = 1; o < 16; o <<= 1) ls += __shfl_xor(ls, o, 64);
    m_r[r] = M;
    inv_l[r] = 1.f / ls;
  }

  f32x4 co[4];
#pragma unroll
  for (int cf = 0; cf < 4; ++cf) co[cf] = (f32x4){0.f, 0.f, 0.f, 0.f};

  gld_lds16(khb + 0 * 8192 + tid * 16, (LDS_AS char*)&KsH[0][0] + tid * 16);
  gld_lds16(klb + 0 * 8192 + tid * 16, (LDS_AS char*)&KsL[0][0] + tid * 16);
  gld_lds16(vtb + 0 * 8192 + tid * 16, (LDS_AS char*)&Vt[0][0] + tid * 16);

  // ---- pass 2: P (nt f32 attn out + bf16 Ps) + PV ----
  for (int kt = 0; kt < 16; ++kt) {
    const int buf = kt & 1;
    if (kt < 15) {
      gld_lds16(khb + (kt + 1) * 8192 + tid * 16,
                (LDS_AS char*)&KsH[buf ^ 1][0] + tid * 16);
      gld_lds16(klb + (kt + 1) * 8192 + tid * 16,
                (LDS_AS char*)&KsL[buf ^ 1][0] + tid * 16);
      gld_lds16(vtb + (kt + 1) * 8192 + tid * 16,
                (LDS_AS char*)&Vt[buf ^ 1][0] + tid * 16);
    }
    if (kt == 0) {
      asm volatile("s_waitcnt vmcnt(3)" ::: "memory");
    } else if (kt < 15) {
      asm volatile("s_waitcnt vmcnt(19)" ::: "memory");
    } else {
      asm volatile("s_waitcnt vmcnt(16)" ::: "memory");
    }
    __builtin_amdgcn_s_barrier();
    const char* ksh = KsH[buf];
    const char* ksl = KsL[buf];
    const char* vts = Vt[buf];
#pragma unroll
    for (int nf = 0; nf < 4; ++nf) {
      int row = nf * 16 + lr;
      f32x4 cc = {0.f, 0.f, 0.f, 0.f};
      cc = mfma3(aqh0, aql0, *(const bf16x8*)(ksh + KB(row, q4 * 16)),
                 *(const bf16x8*)(ksl + KB(row, q4 * 16)), cc);
      cc = mfma3(aqh1, aql1, *(const bf16x8*)(ksh + KB(row, 64 + q4 * 16)),
                 *(const bf16x8*)(ksl + KB(row, 64 + q4 * 16)), cc);
#pragma unroll
      for (int r = 0; r < 4; ++r) {
        float p = __expf(cc[r] * 8.f - m_r[r]) * inv_l[r];
        PsH[w][q4 * 4 + r][nf * 16 + lr] = (__bf16)p;
        int arow = rb * 128 + w * 16 + q4 * 4 + r;
        __builtin_nontemporal_store(
            p, &attn_out[((size_t)(g * 1024 + arow)) * 1024 + kt * 64 + nf * 16 + lr]);
      }
    }
#pragma unroll
    for (int kk = 0; kk < 2; ++kk) {
      bf16x8 ph = *(const bf16x8*)&PsH[w][lr][kk * 32 + q4 * 8];
#pragma unroll
      for (int cf = 0; cf < 4; ++cf) {
        bf16x8 vt = *(const bf16x8*)(vts + KB(cf * 16 + lr, kk * 64 + q4 * 16));
        co[cf] = MFMA(ph, vt, co[cf]);
      }
    }
    __builtin_amdgcn_s_barrier();
  }
#pragma unroll
  for (int cf = 0; cf < 4; ++cf)
#pragma unroll
    for (int r = 0; r < 4; ++r) {
      int i = rb * 128 + w * 16 + q4 * 4 + r;
      ctx_out[((size_t)(g * 1024 + i)) * 64 + cf * 16 + lr] = (__bf16)co[cf][r];
    }
}

// ---------------------------------------------------------------------------
// gemm_db: 2-phase double-buffered GEMM (T3-min pipeline).
// C = A[MxK] * Bt[NxK]^T. Tile BM x 128, 4 waves, XCD-chunked 1D grid.
// EPI 1: Outb = bf16(relu(acc+bias)).
// EPI 4: Outb = bf16(acc+bias+Res f32).
// EPI 5: Outb = bf16(acc)   [split-K partial, bf16]
// LDS: 2 x (BM*64 A + 128*64 B) bf16 = 48KB (BM=64) / 64KB (BM=128).
// ---------------------------------------------------------------------------
template <int EPI, int BM>
__global__ __launch_bounds__(256) void gemm_db(
    const __bf16* __restrict__ A, const __bf16* __restrict__ Bt,
    const float* __restrict__ bias, const float* __restrict__ Res,
    __bf16* __restrict__ Outb,
    int M, int N, int K, int Kloop, int nbx, int tiles_per_out)
{
  constexpr int MF = BM / 32;
  constexpr int ELEMS = BM * 64 + 8192;
  __shared__ __attribute__((aligned(16))) __bf16 sm[2][ELEMS];
  const int tid = threadIdx.x;
  const int l = tid & 63, w = tid >> 6;
  const int lr = l & 15, lkb = (l >> 4) * 8;
  const int nwg = gridDim.x;
  const int swz = (blockIdx.x & 7) * (nwg >> 3) + (blockIdx.x >> 3);
  const int ks = swz / tiles_per_out;
  const int tile = swz % tiles_per_out;
  const int m0 = (tile / nbx) * BM, n0 = (tile % nbx) * 128;
  const int kbase = ks * Kloop;
  const int wr = (w >> 1) * (BM / 2), wc = (w & 1) * 64;

  f32x4 acc[MF][4];
  f32x4 zero = {0.f, 0.f, 0.f, 0.f};
#pragma unroll
  for (int m = 0; m < MF; ++m)
#pragma unroll
    for (int n = 0; n < 4; ++n) acc[m][n] = zero;

  const int nkt = Kloop >> 6;

#define GSTAGE(BUF, KT)                                                        \
  {                                                                            \
    LDS_AS char* dst = (LDS_AS char*)&sm[(BUF)][0];                            \
    _Pragma("unroll") for (int it = 0; it < MF; ++it) {                        \
      int slot = it * 256 + tid;                                               \
      int row = slot >> 3, cb = slot & 7;                                      \
      gld_lds16(&A[(size_t)(m0 + row) * K + kbase + (KT) * 64 + cb * 8],       \
                dst + slot * 16);                                              \
    }                                                                          \
    _Pragma("unroll") for (int it = 0; it < 4; ++it) {                         \
      int slot = it * 256 + tid;                                               \
      int row = slot >> 3, cb = slot & 7;                                      \
      gld_lds16(&Bt[(size_t)(n0 + row) * K + kbase + (KT) * 64 + cb * 8],      \
                dst + BM * 128 + slot * 16);                                   \
    }                                                                          \
  }

  GSTAGE(0, 0);
  for (int kt = 0; kt < nkt; ++kt) {
    const int buf = kt & 1;
    if (kt < nkt - 1) {
      GSTAGE(buf ^ 1, kt + 1);
      if (BM == 64) {
        asm volatile("s_waitcnt vmcnt(6)" ::: "memory");
      } else {
        asm volatile("s_waitcnt vmcnt(8)" ::: "memory");
      }
    } else {
      asm volatile("s_waitcnt vmcnt(0)" ::: "memory");
    }
    __builtin_amdgcn_s_barrier();
    const __bf16* s = &sm[buf][0];
#pragma unroll
    for (int kk = 0; kk < 2; ++kk) {
      bf16x8 a[MF], b[4];
#pragma unroll
      for (int m = 0; m < MF; ++m)
        a[m] = *(const bf16x8*)&s[(wr + m * 16 + lr) * 64 + kk * 32 + lkb];
#pragma unroll
      for (int n = 0; n < 4; ++n)
        b[n] = *(const bf16x8*)&s[BM * 64 + (wc + n * 16 + lr) * 64 + kk * 32 + lkb];
#pragma unroll
      for (int m = 0; m < MF; ++m)
#pragma unroll
        for (int n = 0; n < 4; ++n) acc[m][n] = MFMA(a[m], b[n], acc[m][n]);
    }
    __builtin_amdgcn_s_barrier();
  }
#undef GSTAGE

  __bf16* outp = (EPI == 5) ? Outb + (size_t)ks * M * N : Outb;
#pragma unroll
  for (int n = 0; n < 4; ++n) {
    int gcol = n0 + wc + n * 16 + lr;
    float bc = (EPI == 5) ? 0.f : bias[gcol];
#pragma unroll
    for (int m = 0; m < MF; ++m) {
      int grow = m0 + wr + m * 16 + (l >> 4) * 4;
#pragma unroll
      for (int r = 0; r < 4; ++r) {
        float v = acc[m][n][r] + bc;
        size_t o = (size_t)(grow + r) * N + gcol;
        if (EPI == 1) {
          outp[o] = (__bf16)fmaxf(v, 0.f);
        } else if (EPI == 4) {
          outp[o] = (__bf16)(v + Res[o]);
        } else {
          outp[o] = (__bf16)v;
        }
      }
    }
  }
}

// ---------------------------------------------------------------------------
// LayerNorm over D=1024, bf16 in -> bf16 out, one block per row.
// ---------------------------------------------------------------------------
__global__ __launch_bounds__(256) void ln_b2b(
    const __bf16* __restrict__ in, const float* __restrict__ gam,
    const float* __restrict__ bet, __bf16* __restrict__ outB)
{
  __shared__ float red[8];
  const int row = blockIdx.x, t = threadIdx.x;
  bf16x4 vb = ((const bf16x4*)(in + (size_t)row * 1024))[t];
  float v[4];
  float s = 0.f, ss = 0.f;
#pragma unroll
  for (int j = 0; j < 4; ++j) {
    v[j] = (float)vb[j];
    s += v[j];
    ss += v[j] * v[j];
  }
#pragma unroll
  for (int o = 1; o < 64; o <<= 1) {
    s += __shfl_xor(s, o, 64);
    ss += __shfl_xor(ss, o, 64);
  }
  int w = t >> 6, l = t & 63;
  if (l == 0) { red[w] = s; red[4 + w] = ss; }
  __syncthreads();
  float S = red[0] + red[1] + red[2] + red[3];
  float SS = red[4] + red[5] + red[6] + red[7];
  float mean = S * (1.f / 1024.f);
  float var = SS * (1.f / 1024.f) - mean * mean;
  float rstd = rsqrtf(var + 1e-5f);
  bf16x4 ob;
#pragma unroll
  for (int j = 0; j < 4; ++j) {
    int col = t * 4 + j;
    ob[j] = (__bf16)((v[j] - mean) * rstd * gam[col] + bet[col]);
  }
  ((bf16x4*)(outB + (size_t)row * 1024))[t] = ob;
}

// ---------------------------------------------------------------------------
// Fused final LN: x = P0b + P1b (bf16 partials) + bias + resB, out = LN (f32)
// ---------------------------------------------------------------------------
__global__ __launch_bounds__(256) void ln_fuse2(
    const __bf16* __restrict__ P0, const __bf16* __restrict__ P1,
    const float* __restrict__ bias, const __bf16* __restrict__ resB,
    const float* __restrict__ gam, const float* __restrict__ bet,
    float* __restrict__ out)
{
  __shared__ float red[8];
  const int row = blockIdx.x, t = threadIdx.x;
  const size_t ro = (size_t)row * 1024;
  bf16x4 p0 = ((const bf16x4*)(P0 + ro))[t];
  bf16x4 p1 = ((const bf16x4*)(P1 + ro))[t];
  f32x4 bi = ((const f32x4*)bias)[t];
  bf16x4 rb = ((const bf16x4*)(resB + ro))[t];
  f32x4 v;
  float s = 0.f, ss = 0.f;
#pragma unroll
  for (int j = 0; j < 4; ++j) {
    v[j] = (float)p0[j] + (float)p1[j] + bi[j] + (float)rb[j];
    s += v[j];
    ss += v[j] * v[j];
  }
#pragma unroll
  for (int o = 1; o < 64; o <<= 1) {
    s += __shfl_xor(s, o, 64);
    ss += __shfl_xor(ss, o, 64);
  }
  int w = t >> 6, l = t & 63;
  if (l == 0) { red[w] = s; red[4 + w] = ss; }
  __syncthreads();
  float S = red[0] + red[1] + red[2] + red[3];
  float SS = red[4] + red[5] + red[6] + red[7];
  float mean = S * (1.f / 1024.f);
  float var = SS * (1.f / 1024.f) - mean * mean;
  float rstd = rsqrtf(var + 1e-5f);
  f32x4 ov;
#pragma unroll
  for (int j = 0; j < 4; ++j) {
    int col = t * 4 + j;
    ov[j] = (v[j] - mean) * rstd * gam[col] + bet[col];
  }
  ((f32x4*)(out + ro))[t] = ov;
}

// ---------------------------------------------------------------------------
extern "C" void kernel_launch(void* const* d_in, const int* in_sizes, int n_in,
                              void* d_out, int out_size, void* d_ws, size_t ws_size,
                              hipStream_t stream) {
  const float* k_in = (const float*)d_in[0];
  const float* v_in = (const float*)d_in[1];
  const float* q_in = (const float*)d_in[2];
  const float* r_in = (const float*)d_in[3];
  const float* Wf = (const float*)d_in[4];
  const float* bf = (const float*)d_in[5];
  const float* g1 = (const float*)d_in[6];
  const float* b1 = (const float*)d_in[7];
  const float* W1 = (const float*)d_in[8];
  const float* bw1 = (const float*)d_in[9];
  const float* W2 = (const float*)d_in[10];
  const float* bw2 = (const float*)d_in[11];
  const float* g2 = (const float*)d_in[12];
  const float* b2 = (const float*)d_in[13];

  float* out0 = (float*)d_out;          // [4096,1024]
  float* attn = out0 + 4194304;         // [64,1024,1024]

  char* W = (char*)d_ws;
  const size_t MB = 1024 * 1024;
  char* KHimg = W + 0;                   // 8MB
  char* KLimg = W + 8 * MB;              // 8MB
  char* VTimg = W + 16 * MB;             // 8MB
  __bf16* WFT = (__bf16*)(W + 24 * MB);  // 2MB
  __bf16* W1T = (__bf16*)(W + 26 * MB);  // 8MB
  __bf16* W2T = (__bf16*)(W + 34 * MB);  // 8MB
  __bf16* CTX = (__bf16*)(W + 42 * MB);  // 8MB
  __bf16* Xb = (__bf16*)(W + 50 * MB);   // 8MB
  __bf16* Hb = (__bf16*)(W + 58 * MB);   // 32MB
  __bf16* T1b = (__bf16*)(W + 90 * MB);  // 8MB
  __bf16* P0b = (__bf16*)(W + 98 * MB);  // 8MB split-K partial 0 (bf16)
  __bf16* P1b = (__bf16*)(W + 106 * MB); // 8MB split-K partial 1 (bf16)

  prep_all<<<11264, 256, 0, stream>>>(k_in, q_in, KHimg, KLimg, VTimg,
                                      Wf, WFT, W1, W1T, W2, W2T);

  attn_v8<<<512, 512, 0, stream>>>(v_in, KHimg, KLimg, VTimg, attn, CTX);

  // t1 = bf16(r + ctx @ Wf + bf)   [dbuf]
  gemm_db<4, 64><<<512, 256, 0, stream>>>(CTX, WFT, bf, r_in, T1b,
                                          4096, 1024, 1024, 1024, 8, 512);
  // x = LN(t1) -> bf16
  ln_b2b<<<4096, 256, 0, stream>>>(T1b, g1, b1, Xb);
  // h = relu(x @ W1 + bw1) -> bf16  [dbuf, was sync]
  gemm_db<1, 128><<<1024, 256, 0, stream>>>(Xb, W1T, bw1, nullptr, Hb,
                                            4096, 4096, 1024, 1024, 32, 1024);
  // split-K=2 bf16 partials of h @ W2  [dbuf]
  gemm_db<5, 128><<<512, 256, 0, stream>>>(Hb, W2T, nullptr, nullptr, P0b,
                                           4096, 1024, 4096, 2048, 8, 256);
  // out = LN(P0b + P1b + bw2 + x)
  ln_fuse2<<<4096, 256, 0, stream>>>(P0b, P1b, bw2, Xb, g2, b2, out0);
}

// Round 14
// 233.803 us; speedup vs baseline: 1.4054x; 1.1500x over previous
//
#include <hip/hip_runtime.h>
#include <hip/hip_bf16.h>
#include <cstdint>

typedef __attribute__((ext_vector_type(8))) __bf16 bf16x8;
typedef __attribute__((ext_vector_type(4))) __bf16 bf16x4;
typedef __attribute__((ext_vector_type(4))) float f32x4;
typedef unsigned int uint32;
typedef unsigned short uint16;

#define LDS_AS __attribute__((address_space(3)))
#define GLB_AS __attribute__((address_space(1)))

static __device__ __forceinline__ void gld_lds16(const void* g, LDS_AS char* l) {
  __builtin_amdgcn_global_load_lds((const GLB_AS uint32*)g, (LDS_AS uint32*)l, 16, 0, 0);
}

#define MFMA(a, b, c) __builtin_amdgcn_mfma_f32_16x16x32_bf16((a), (b), (c), 0, 0, 0)

// 3-term split-bf16 MFMA: A*B ~= Ah*Bh + Al*Bh + Ah*Bl
static __device__ __forceinline__ f32x4 mfma3(bf16x8 ah, bf16x8 al, bf16x8 bh,
                                              bf16x8 bl, f32x4 c) {
  c = MFMA(ah, bh, c);
  c = MFMA(al, bh, c);
  c = MFMA(ah, bl, c);
  return c;
}

static __device__ __forceinline__ uint32 pack_bf16(float a, float b) {
  __bf16 ha = (__bf16)a, hb = (__bf16)b;
  return (uint32)__builtin_bit_cast(uint16, ha) |
         ((uint32)__builtin_bit_cast(uint16, hb) << 16);
}

// XOR swizzle: spreads stride-128B rows across banks (T2, rule #21 both-sides)
#define KB(row, colbyte) ((((row) * 128 + (colbyte))) ^ (((row) & 7) << 4))

// ---------------------------------------------------------------------------
// prep_all: one dispatch for all input preprocessing.
//  blocks 0..1023     : K f32 -> split bf16 hi/lo swizzled images KH/KL
//  blocks 1024..2047  : V f32 -> V^T swizzled image, k-pairs packed u32
//  blocks 2048..3071  : Wf  transpose -> bf16 WFT  [1024x1024]
//  blocks 3072..7167  : W1  transpose -> bf16 W1T  [4096x1024]
//  blocks 7168..11263 : W2  transpose -> bf16 W2T  [1024x4096]
// ---------------------------------------------------------------------------
__global__ __launch_bounds__(256) void prep_all(
    const float* __restrict__ K, const float* __restrict__ V,
    char* __restrict__ KH, char* __restrict__ KL, char* __restrict__ VT,
    const float* __restrict__ Wf, __bf16* __restrict__ WFT,
    const float* __restrict__ W1, __bf16* __restrict__ W1T,
    const float* __restrict__ W2, __bf16* __restrict__ W2T) {
  int b = blockIdx.x;
  if (b < 1024) {
    int kt = b & 15, h = b >> 4;
    const float* src = K + (size_t)h * 65536 + kt * 4096;
    char* dh = KH + (size_t)(h * 16 + kt) * 8192;
    char* dl = KL + (size_t)(h * 16 + kt) * 8192;
    int r = threadIdx.x >> 2, cq = threadIdx.x & 3;
    const float* sp = src + r * 64 + cq * 16;
    bf16x8 h0, l0, h1, l1;
#pragma unroll
    for (int j = 0; j < 8; ++j) {
      float x0 = sp[j], x1 = sp[8 + j];
      __bf16 a = (__bf16)x0, bb = (__bf16)x1;
      h0[j] = a; l0[j] = (__bf16)(x0 - (float)a);
      h1[j] = bb; l1[j] = (__bf16)(x1 - (float)bb);
    }
    int sw = (r & 7) << 4;
    int o0 = (r * 128 + cq * 32) ^ sw;
    int o1 = (r * 128 + cq * 32 + 16) ^ sw;
    *(bf16x8*)(dh + o0) = h0;
    *(bf16x8*)(dh + o1) = h1;
    *(bf16x8*)(dl + o0) = l0;
    *(bf16x8*)(dl + o1) = l1;
    return;
  }
  if (b < 2048) {
    b -= 1024;
    int kt = b & 15, h = b >> 4;
    const float* src = V + (size_t)h * 65536 + kt * 4096;
    char* dv = VT + (size_t)(h * 16 + kt) * 8192;
    int kp = threadIdx.x >> 3, dq = threadIdx.x & 7;
    const float* s0 = src + (2 * kp) * 64 + dq * 8;
    const float* s1 = s0 + 64;
#pragma unroll
    for (int j = 0; j < 8; ++j) {
      uint32 pk = pack_bf16(s0[j], s1[j]);
      int d = dq * 8 + j;
      *(uint32*)(dv + ((d * 128 + kp * 4) ^ ((d & 7) << 4))) = pk;
    }
    return;
  }
  // transposes
  const float* in;
  __bf16* out;
  int R, C, bx, by;
  if (b < 3072) {
    b -= 2048; in = Wf; out = WFT; R = 1024; C = 1024;
    bx = (b & 31) * 32; by = (b >> 5) * 32;
  } else if (b < 7168) {
    b -= 3072; in = W1; out = W1T; R = 1024; C = 4096;
    bx = (b & 127) * 32; by = (b >> 7) * 32;
  } else {
    b -= 7168; in = W2; out = W2T; R = 4096; C = 1024;
    bx = (b & 31) * 32; by = (b >> 5) * 32;
  }
  __shared__ float tile[32][33];
  int tx = threadIdx.x & 31, ty = threadIdx.x >> 5;
  for (int i = ty; i < 32; i += 8)
    tile[i][tx] = in[(size_t)(by + i) * C + bx + tx];
  __syncthreads();
  for (int i = ty; i < 32; i += 8)
    out[(size_t)(bx + i) * R + by + tx] = (__bf16)tile[tx][i];
}

// ---------------------------------------------------------------------------
// Attention v9: v8 + coalesced P store. The nf-loop writes only PsH (bf16);
// a wave-local store phase reads back bf16x4 and issues 4 f32x4 nt stores
// per lane per tile (256B row segments) instead of 16 scalar dword stores.
// Block = (head g, 128-row q block rb), 8 waves x 16 q rows.
// Q = v_input, K = k_input, V = q_input (reference signature quirk).
// ---------------------------------------------------------------------------
__global__ __launch_bounds__(512, 4) void attn_v9(
    const float* __restrict__ Qin, const char* __restrict__ KHimg,
    const char* __restrict__ KLimg, const char* __restrict__ VTimg,
    float* __restrict__ attn_out, __bf16* __restrict__ ctx_out)
{
  __shared__ __attribute__((aligned(16))) char KsH[2][8192];
  __shared__ __attribute__((aligned(16))) char KsL[2][8192];
  __shared__ __attribute__((aligned(16))) char Vt[2][8192];
  __shared__ __attribute__((aligned(16))) __bf16 PsH[8][16][72];

  const int tid = threadIdx.x;
  const int l = tid & 63, w = tid >> 6;
  const int lr = l & 15, q4 = l >> 4;
  const int swz = (blockIdx.x & 7) * 64 + (blockIdx.x >> 3);  // XCD chunking
  const int g = swz >> 3, rb = swz & 7;
  const size_t base = (size_t)g * 65536;
  const char* khb = KHimg + (size_t)g * 131072;
  const char* klb = KLimg + (size_t)g * 131072;
  const char* vtb = VTimg + (size_t)g * 131072;

  const float* qp = Qin + base + (size_t)(rb * 128 + w * 16 + lr) * 64;
  f32x4 qv[4];
#pragma unroll
  for (int j = 0; j < 2; ++j) {
    qv[j] = *(const f32x4*)&qp[q4 * 8 + j * 4];
    qv[2 + j] = *(const f32x4*)&qp[32 + q4 * 8 + j * 4];
  }

  gld_lds16(khb + 0 * 8192 + tid * 16, (LDS_AS char*)&KsH[0][0] + tid * 16);
  gld_lds16(klb + 0 * 8192 + tid * 16, (LDS_AS char*)&KsL[0][0] + tid * 16);

  bf16x8 aqh0, aql0, aqh1, aql1;
#pragma unroll
  for (int j = 0; j < 8; ++j) {
    float x0 = qv[j >> 2][j & 3];
    float x1 = qv[2 + (j >> 2)][j & 3];
    __bf16 h0 = (__bf16)x0, h1 = (__bf16)x1;
    aqh0[j] = h0; aql0[j] = (__bf16)(x0 - (float)h0);
    aqh1[j] = h1; aql1[j] = (__bf16)(x1 - (float)h1);
  }

  float m_r[4], ll_r[4];
#pragma unroll
  for (int r = 0; r < 4; ++r) { m_r[r] = -1e30f; ll_r[r] = 0.f; }

  // ---- pass 1: stats (lane-local online softmax, zero shfl in loop) ----
  for (int kt = 0; kt < 16; ++kt) {
    const int buf = kt & 1;
    if (kt < 15) {
      gld_lds16(khb + (kt + 1) * 8192 + tid * 16,
                (LDS_AS char*)&KsH[buf ^ 1][0] + tid * 16);
      gld_lds16(klb + (kt + 1) * 8192 + tid * 16,
                (LDS_AS char*)&KsL[buf ^ 1][0] + tid * 16);
      asm volatile("s_waitcnt vmcnt(2)" ::: "memory");
    } else {
      asm volatile("s_waitcnt vmcnt(0)" ::: "memory");
    }
    __builtin_amdgcn_s_barrier();
    const char* ksh = KsH[buf];
    const char* ksl = KsL[buf];
    f32x4 c[4];
#pragma unroll
    for (int nf = 0; nf < 4; ++nf) {
      int row = nf * 16 + lr;
      f32x4 cc = {0.f, 0.f, 0.f, 0.f};
      cc = mfma3(aqh0, aql0, *(const bf16x8*)(ksh + KB(row, q4 * 16)),
                 *(const bf16x8*)(ksl + KB(row, q4 * 16)), cc);
      cc = mfma3(aqh1, aql1, *(const bf16x8*)(ksh + KB(row, 64 + q4 * 16)),
                 *(const bf16x8*)(ksl + KB(row, 64 + q4 * 16)), cc);
      c[nf] = cc;
    }
#pragma unroll
    for (int r = 0; r < 4; ++r) {
      float s0 = c[0][r] * 8.f, s1 = c[1][r] * 8.f;
      float s2 = c[2][r] * 8.f, s3 = c[3][r] * 8.f;
      float lm = fmaxf(fmaxf(s0, s1), fmaxf(s2, s3));
      float mnew = fmaxf(m_r[r], lm);
      ll_r[r] = ll_r[r] * __expf(m_r[r] - mnew) +
                (__expf(s0 - mnew) + __expf(s1 - mnew) +
                 __expf(s2 - mnew) + __expf(s3 - mnew));
      m_r[r] = mnew;
    }
    __builtin_amdgcn_s_barrier();
  }
  float inv_l[4];
#pragma unroll
  for (int r = 0; r < 4; ++r) {
    float M = m_r[r];
#pragma unroll
    for (int o = 1; o < 16; o <<= 1) M = fmaxf(M, __shfl_xor(M, o, 64));
    float ls = ll_r[r] * __expf(m_r[r] - M);
#pragma unroll
    for (int o = 1; o < 16; o <<= 1) ls += __shfl_xor(ls, o, 64);
    m_r[r] = M;
    inv_l[r] = 1.f / ls;
  }

  f32x4 co[4];
#pragma unroll
  for (int cf = 0; cf < 4; ++cf) co[cf] = (f32x4){0.f, 0.f, 0.f, 0.f};

  gld_lds16(khb + 0 * 8192 + tid * 16, (LDS_AS char*)&KsH[0][0] + tid * 16);
  gld_lds16(klb + 0 * 8192 + tid * 16, (LDS_AS char*)&KsL[0][0] + tid * 16);
  gld_lds16(vtb + 0 * 8192 + tid * 16, (LDS_AS char*)&Vt[0][0] + tid * 16);

  // ---- pass 2: P (PsH bf16 -> coalesced nt f32x4 store) + PV ----
  // vmcnt ledger per lane: 3 loads/STAGE, 4 f32x4 stores/tile.
  for (int kt = 0; kt < 16; ++kt) {
    const int buf = kt & 1;
    if (kt < 15) {
      gld_lds16(khb + (kt + 1) * 8192 + tid * 16,
                (LDS_AS char*)&KsH[buf ^ 1][0] + tid * 16);
      gld_lds16(klb + (kt + 1) * 8192 + tid * 16,
                (LDS_AS char*)&KsL[buf ^ 1][0] + tid * 16);
      gld_lds16(vtb + (kt + 1) * 8192 + tid * 16,
                (LDS_AS char*)&Vt[buf ^ 1][0] + tid * 16);
    }
    if (kt == 0) {
      asm volatile("s_waitcnt vmcnt(3)" ::: "memory");
    } else if (kt < 15) {
      asm volatile("s_waitcnt vmcnt(7)" ::: "memory");
    } else {
      asm volatile("s_waitcnt vmcnt(4)" ::: "memory");
    }
    __builtin_amdgcn_s_barrier();
    const char* ksh = KsH[buf];
    const char* ksl = KsL[buf];
    const char* vts = Vt[buf];
#pragma unroll
    for (int nf = 0; nf < 4; ++nf) {
      int row = nf * 16 + lr;
      f32x4 cc = {0.f, 0.f, 0.f, 0.f};
      cc = mfma3(aqh0, aql0, *(const bf16x8*)(ksh + KB(row, q4 * 16)),
                 *(const bf16x8*)(ksl + KB(row, q4 * 16)), cc);
      cc = mfma3(aqh1, aql1, *(const bf16x8*)(ksh + KB(row, 64 + q4 * 16)),
                 *(const bf16x8*)(ksl + KB(row, 64 + q4 * 16)), cc);
#pragma unroll
      for (int r = 0; r < 4; ++r) {
        float p = __expf(cc[r] * 8.f - m_r[r]) * inv_l[r];
        PsH[w][q4 * 4 + r][nf * 16 + lr] = (__bf16)p;
      }
    }
    // coalesced nt store: wave's own 16x64 tile, 4 rows x 256B per instr
    {
      const int rbase = g * 1024 + rb * 128 + w * 16;
#pragma unroll
      for (int it = 0; it < 4; ++it) {
        int prow = it * 4 + q4;
        int pcol = lr * 4;
        bf16x4 pb = *(const bf16x4*)&PsH[w][prow][pcol];
        f32x4 pf;
#pragma unroll
        for (int j = 0; j < 4; ++j) pf[j] = (float)pb[j];
        __builtin_nontemporal_store(
            pf, (f32x4*)&attn_out[((size_t)(rbase + prow)) * 1024 + kt * 64 + pcol]);
      }
    }
    // PV: PsH[w] same-wave; Vt[buf] staged this tile
#pragma unroll
    for (int kk = 0; kk < 2; ++kk) {
      bf16x8 ph = *(const bf16x8*)&PsH[w][lr][kk * 32 + q4 * 8];
#pragma unroll
      for (int cf = 0; cf < 4; ++cf) {
        bf16x8 vt = *(const bf16x8*)(vts + KB(cf * 16 + lr, kk * 64 + q4 * 16));
        co[cf] = MFMA(ph, vt, co[cf]);
      }
    }
    __builtin_amdgcn_s_barrier();
  }
#pragma unroll
  for (int cf = 0; cf < 4; ++cf)
#pragma unroll
    for (int r = 0; r < 4; ++r) {
      int i = rb * 128 + w * 16 + q4 * 4 + r;
      ctx_out[((size_t)(g * 1024 + i)) * 64 + cf * 16 + lr] = (__bf16)co[cf][r];
    }
}

// ---------------------------------------------------------------------------
// gemm_db: 2-phase double-buffered GEMM (T3-min pipeline).
// C = A[MxK] * Bt[NxK]^T. Tile BM x 128, 4 waves, XCD-chunked 1D grid.
// EPI 1: Outb = bf16(relu(acc+bias)).
// EPI 4: Outb = bf16(acc+bias+Res f32).
// EPI 5: Outb = bf16(acc)   [split-K partial, bf16]
// LDS: 2 x (BM*64 A + 128*64 B) bf16 = 48KB (BM=64) / 64KB (BM=128).
// ---------------------------------------------------------------------------
template <int EPI, int BM>
__global__ __launch_bounds__(256) void gemm_db(
    const __bf16* __restrict__ A, const __bf16* __restrict__ Bt,
    const float* __restrict__ bias, const float* __restrict__ Res,
    __bf16* __restrict__ Outb,
    int M, int N, int K, int Kloop, int nbx, int tiles_per_out)
{
  constexpr int MF = BM / 32;
  constexpr int ELEMS = BM * 64 + 8192;
  __shared__ __attribute__((aligned(16))) __bf16 sm[2][ELEMS];
  const int tid = threadIdx.x;
  const int l = tid & 63, w = tid >> 6;
  const int lr = l & 15, lkb = (l >> 4) * 8;
  const int nwg = gridDim.x;
  const int swz = (blockIdx.x & 7) * (nwg >> 3) + (blockIdx.x >> 3);
  const int ks = swz / tiles_per_out;
  const int tile = swz % tiles_per_out;
  const int m0 = (tile / nbx) * BM, n0 = (tile % nbx) * 128;
  const int kbase = ks * Kloop;
  const int wr = (w >> 1) * (BM / 2), wc = (w & 1) * 64;

  f32x4 acc[MF][4];
  f32x4 zero = {0.f, 0.f, 0.f, 0.f};
#pragma unroll
  for (int m = 0; m < MF; ++m)
#pragma unroll
    for (int n = 0; n < 4; ++n) acc[m][n] = zero;

  const int nkt = Kloop >> 6;

#define GSTAGE(BUF, KT)                                                        \
  {                                                                            \
    LDS_AS char* dst = (LDS_AS char*)&sm[(BUF)][0];                            \
    _Pragma("unroll") for (int it = 0; it < MF; ++it) {                        \
      int slot = it * 256 + tid;                                               \
      int row = slot >> 3, cb = slot & 7;                                      \
      gld_lds16(&A[(size_t)(m0 + row) * K + kbase + (KT) * 64 + cb * 8],       \
                dst + slot * 16);                                              \
    }                                                                          \
    _Pragma("unroll") for (int it = 0; it < 4; ++it) {                         \
      int slot = it * 256 + tid;                                               \
      int row = slot >> 3, cb = slot & 7;                                      \
      gld_lds16(&Bt[(size_t)(n0 + row) * K + kbase + (KT) * 64 + cb * 8],      \
                dst + BM * 128 + slot * 16);                                   \
    }                                                                          \
  }

  GSTAGE(0, 0);
  for (int kt = 0; kt < nkt; ++kt) {
    const int buf = kt & 1;
    if (kt < nkt - 1) {
      GSTAGE(buf ^ 1, kt + 1);
      if (BM == 64) {
        asm volatile("s_waitcnt vmcnt(6)" ::: "memory");
      } else {
        asm volatile("s_waitcnt vmcnt(8)" ::: "memory");
      }
    } else {
      asm volatile("s_waitcnt vmcnt(0)" ::: "memory");
    }
    __builtin_amdgcn_s_barrier();
    const __bf16* s = &sm[buf][0];
#pragma unroll
    for (int kk = 0; kk < 2; ++kk) {
      bf16x8 a[MF], b[4];
#pragma unroll
      for (int m = 0; m < MF; ++m)
        a[m] = *(const bf16x8*)&s[(wr + m * 16 + lr) * 64 + kk * 32 + lkb];
#pragma unroll
      for (int n = 0; n < 4; ++n)
        b[n] = *(const bf16x8*)&s[BM * 64 + (wc + n * 16 + lr) * 64 + kk * 32 + lkb];
#pragma unroll
      for (int m = 0; m < MF; ++m)
#pragma unroll
        for (int n = 0; n < 4; ++n) acc[m][n] = MFMA(a[m], b[n], acc[m][n]);
    }
    __builtin_amdgcn_s_barrier();
  }
#undef GSTAGE

  __bf16* outp = (EPI == 5) ? Outb + (size_t)ks * M * N : Outb;
#pragma unroll
  for (int n = 0; n < 4; ++n) {
    int gcol = n0 + wc + n * 16 + lr;
    float bc = (EPI == 5) ? 0.f : bias[gcol];
#pragma unroll
    for (int m = 0; m < MF; ++m) {
      int grow = m0 + wr + m * 16 + (l >> 4) * 4;
#pragma unroll
      for (int r = 0; r < 4; ++r) {
        float v = acc[m][n][r] + bc;
        size_t o = (size_t)(grow + r) * N + gcol;
        if (EPI == 1) {
          outp[o] = (__bf16)fmaxf(v, 0.f);
        } else if (EPI == 4) {
          outp[o] = (__bf16)(v + Res[o]);
        } else {
          outp[o] = (__bf16)v;
        }
      }
    }
  }
}

// ---------------------------------------------------------------------------
// LayerNorm over D=1024, bf16 in -> bf16 out, one block per row.
// ---------------------------------------------------------------------------
__global__ __launch_bounds__(256) void ln_b2b(
    const __bf16* __restrict__ in, const float* __restrict__ gam,
    const float* __restrict__ bet, __bf16* __restrict__ outB)
{
  __shared__ float red[8];
  const int row = blockIdx.x, t = threadIdx.x;
  bf16x4 vb = ((const bf16x4*)(in + (size_t)row * 1024))[t];
  float v[4];
  float s = 0.f, ss = 0.f;
#pragma unroll
  for (int j = 0; j < 4; ++j) {
    v[j] = (float)vb[j];
    s += v[j];
    ss += v[j] * v[j];
  }
#pragma unroll
  for (int o = 1; o < 64; o <<= 1) {
    s += __shfl_xor(s, o, 64);
    ss += __shfl_xor(ss, o, 64);
  }
  int w = t >> 6, l = t & 63;
  if (l == 0) { red[w] = s; red[4 + w] = ss; }
  __syncthreads();
  float S = red[0] + red[1] + red[2] + red[3];
  float SS = red[4] + red[5] + red[6] + red[7];
  float mean = S * (1.f / 1024.f);
  float var = SS * (1.f / 1024.f) - mean * mean;
  float rstd = rsqrtf(var + 1e-5f);
  bf16x4 ob;
#pragma unroll
  for (int j = 0; j < 4; ++j) {
    int col = t * 4 + j;
    ob[j] = (__bf16)((v[j] - mean) * rstd * gam[col] + bet[col]);
  }
  ((bf16x4*)(outB + (size_t)row * 1024))[t] = ob;
}

// ---------------------------------------------------------------------------
// Fused final LN: x = P0..P3 (bf16 split-K partials) + bias + resB, LN -> f32
// ---------------------------------------------------------------------------
__global__ __launch_bounds__(256) void ln_fuse4(
    const __bf16* __restrict__ Pb, const float* __restrict__ bias,
    const __bf16* __restrict__ resB, const float* __restrict__ gam,
    const float* __restrict__ bet, float* __restrict__ out)
{
  __shared__ float red[8];
  const int row = blockIdx.x, t = threadIdx.x;
  const size_t ro = (size_t)row * 1024;
  bf16x4 p0 = ((const bf16x4*)(Pb + ro))[t];
  bf16x4 p1 = ((const bf16x4*)(Pb + 4194304 + ro))[t];
  bf16x4 p2 = ((const bf16x4*)(Pb + 8388608 + ro))[t];
  bf16x4 p3 = ((const bf16x4*)(Pb + 12582912 + ro))[t];
  f32x4 bi = ((const f32x4*)bias)[t];
  bf16x4 rb = ((const bf16x4*)(resB + ro))[t];
  f32x4 v;
  float s = 0.f, ss = 0.f;
#pragma unroll
  for (int j = 0; j < 4; ++j) {
    v[j] = (float)p0[j] + (float)p1[j] + (float)p2[j] + (float)p3[j] +
           bi[j] + (float)rb[j];
    s += v[j];
    ss += v[j] * v[j];
  }
#pragma unroll
  for (int o = 1; o < 64; o <<= 1) {
    s += __shfl_xor(s, o, 64);
    ss += __shfl_xor(ss, o, 64);
  }
  int w = t >> 6, l = t & 63;
  if (l == 0) { red[w] = s; red[4 + w] = ss; }
  __syncthreads();
  float S = red[0] + red[1] + red[2] + red[3];
  float SS = red[4] + red[5] + red[6] + red[7];
  float mean = S * (1.f / 1024.f);
  float var = SS * (1.f / 1024.f) - mean * mean;
  float rstd = rsqrtf(var + 1e-5f);
  f32x4 ov;
#pragma unroll
  for (int j = 0; j < 4; ++j) {
    int col = t * 4 + j;
    ov[j] = (v[j] - mean) * rstd * gam[col] + bet[col];
  }
  ((f32x4*)(out + ro))[t] = ov;
}

// ---------------------------------------------------------------------------
extern "C" void kernel_launch(void* const* d_in, const int* in_sizes, int n_in,
                              void* d_out, int out_size, void* d_ws, size_t ws_size,
                              hipStream_t stream) {
  const float* k_in = (const float*)d_in[0];
  const float* v_in = (const float*)d_in[1];
  const float* q_in = (const float*)d_in[2];
  const float* r_in = (const float*)d_in[3];
  const float* Wf = (const float*)d_in[4];
  const float* bf = (const float*)d_in[5];
  const float* g1 = (const float*)d_in[6];
  const float* b1 = (const float*)d_in[7];
  const float* W1 = (const float*)d_in[8];
  const float* bw1 = (const float*)d_in[9];
  const float* W2 = (const float*)d_in[10];
  const float* bw2 = (const float*)d_in[11];
  const float* g2 = (const float*)d_in[12];
  const float* b2 = (const float*)d_in[13];

  float* out0 = (float*)d_out;          // [4096,1024]
  float* attn = out0 + 4194304;         // [64,1024,1024]

  char* W = (char*)d_ws;
  const size_t MB = 1024 * 1024;
  char* KHimg = W + 0;                   // 8MB
  char* KLimg = W + 8 * MB;              // 8MB
  char* VTimg = W + 16 * MB;             // 8MB
  __bf16* WFT = (__bf16*)(W + 24 * MB);  // 2MB
  __bf16* W1T = (__bf16*)(W + 26 * MB);  // 8MB
  __bf16* W2T = (__bf16*)(W + 34 * MB);  // 8MB
  __bf16* CTX = (__bf16*)(W + 42 * MB);  // 8MB
  __bf16* Xb = (__bf16*)(W + 50 * MB);   // 8MB
  __bf16* Hb = (__bf16*)(W + 58 * MB);   // 32MB
  __bf16* T1b = (__bf16*)(W + 90 * MB);  // 8MB
  __bf16* Pb = (__bf16*)(W + 98 * MB);   // 32MB split-K partials x4 (bf16)

  prep_all<<<11264, 256, 0, stream>>>(k_in, q_in, KHimg, KLimg, VTimg,
                                      Wf, WFT, W1, W1T, W2, W2T);

  attn_v9<<<512, 512, 0, stream>>>(v_in, KHimg, KLimg, VTimg, attn, CTX);

  // t1 = bf16(r + ctx @ Wf + bf)   [dbuf]
  gemm_db<4, 64><<<512, 256, 0, stream>>>(CTX, WFT, bf, r_in, T1b,
                                          4096, 1024, 1024, 1024, 8, 512);
  // x = LN(t1) -> bf16
  ln_b2b<<<4096, 256, 0, stream>>>(T1b, g1, b1, Xb);
  // h = relu(x @ W1 + bw1) -> bf16  [dbuf]
  gemm_db<1, 128><<<1024, 256, 0, stream>>>(Xb, W1T, bw1, nullptr, Hb,
                                            4096, 4096, 1024, 1024, 32, 1024);
  // split-K=4 bf16 partials of h @ W2  [dbuf]
  gemm_db<5, 128><<<1024, 256, 0, stream>>>(Hb, W2T, nullptr, nullptr, Pb,
                                            4096, 1024, 4096, 1024, 8, 256);
  // out = LN(P0+P1+P2+P3 + bw2 + x)
  ln_fuse4<<<4096, 256, 0, stream>>>(Pb, bw2, Xb, g2, b2, out0);
}